// Round 3
// baseline (3257.954 us; speedup 1.0000x reference)
//
#include <hip/hip_runtime.h>
#include <hip/hip_bf16.h>

typedef __attribute__((ext_vector_type(4))) float f32x4;
typedef __attribute__((ext_vector_type(8))) short bf16x8;

#define NB 1024   // batch
#define ND 128    // time steps
#define NI 64     // input dim
#define NH 256    // dec hidden
#define NHE 512   // enc hidden
#define KENC 576  // NI + NHE
#define NENC 2048 // 4*NHE
#define KDEC 256

__device__ __forceinline__ float sigmf(float x) { return 1.0f / (1.0f + __expf(-x)); }
__device__ __forceinline__ float tanh_f(float x) { return 1.0f - 2.0f / (__expf(2.0f * x) + 1.0f); }

__device__ __forceinline__ f32x4 mfma16(bf16x8 a, bf16x8 b, f32x4 c) {
    return __builtin_amdgcn_mfma_f32_16x16x32_bf16(a, b, c, 0, 0, 0);
}

__device__ __forceinline__ void spin_ge(const int* p, int target) {
    int g = 0;
    while (__hip_atomic_load(p, __ATOMIC_RELAXED, __HIP_MEMORY_SCOPE_AGENT) < target) {
        __builtin_amdgcn_s_sleep(2);
        if (++g > (1 << 20)) break;   // deadlock bailout -> visible failure, no hang
    }
}

// 4x4 transpose within each lane-quad across regs v0..v3. (verified in round 1)
// In: MFMA frag a, elem v = C[4q+v][lr] (q=lane>>4, lr=lane&15).
// Out: lane holds gates g=0..3 of (row 4q+(lane&3), unit (lr>>2)).
__device__ __forceinline__ void quadtr(f32x4 a, int lane,
                                       float& z0, float& z1, float& z2, float& z3) {
    float x0 = a[0], x1 = a[1], x2 = a[2], x3 = a[3];
    float s0 = __shfl_xor(x0, 1), s1 = __shfl_xor(x1, 1),
          s2 = __shfl_xor(x2, 1), s3 = __shfl_xor(x3, 1);
    bool o1 = (lane & 1) != 0;
    float y0 = o1 ? s1 : x0;
    float y1 = o1 ? x1 : s0;
    float y2 = o1 ? s3 : x2;
    float y3 = o1 ? x3 : s2;
    float t0 = __shfl_xor(y0, 2), t1 = __shfl_xor(y1, 2),
          t2 = __shfl_xor(y2, 2), t3 = __shfl_xor(y3, 2);
    bool o2 = (lane & 2) != 0;
    z0 = o2 ? t2 : y0;
    z1 = o2 ? t3 : y1;
    z2 = o2 ? y2 : t0;
    z3 = o2 ? y3 : t1;
}

// ---------------- packing kernels (unchanged, verified) ----------------

__global__ void pack_enc_kernel(const float* __restrict__ Wx, const float* __restrict__ Wh,
                                const float* __restrict__ bsrc,
                                __hip_bfloat16* __restrict__ Wp, float* __restrict__ bp)
{
    int n = blockIdx.y;
    int k = blockIdx.x * 256 + threadIdx.x;
    int j = n >> 2, g = n & 3;
    int col = g * NHE + j;
    if (k < KENC) {
        float v = (k < NI) ? Wx[k * NENC + col] : Wh[(k - NI) * NENC + col];
        Wp[(size_t)n * KENC + k] = __float2bfloat16(v);
    }
    if (blockIdx.x == 0 && threadIdx.x == 0) bp[n] = bsrc[col];
}

__global__ void pack_dec_kernel(const float* __restrict__ Wh, const float* __restrict__ ow,
                                const float* __restrict__ bsrc,
                                __hip_bfloat16* __restrict__ Wp, float* __restrict__ bp)
{
    int n = blockIdx.y;          // 0..1151
    int k = threadIdx.x;         // 0..255
    float v;
    if (n < 1024) {
        int j = n >> 2, g = n & 3;
        int col = g * NH + j;
        v = Wh[k * 1024 + col];
        if (k == 0) bp[n] = bsrc[col];
    } else if (n < 1088) {
        v = ow[k * NI + (n - 1024)];
    } else {
        v = 0.0f;
    }
    Wp[(size_t)n * KDEC + k] = __float2bfloat16(v);
}

__global__ void pack_xb_kernel(const float* __restrict__ X, const int* __restrict__ W,
                               const float* __restrict__ A, __hip_bfloat16* __restrict__ Xb)
{
    int idx = blockIdx.x * 256 + threadIdx.x;
    int i = idx & 63;
    int t1 = idx >> 6;
    int b = t1 & 1023;
    int d = t1 >> 10;
    int src = (b * ND + d) * NI + i;
    float v = W[src] ? X[src] : A[d * NI + i];
    Xb[idx] = __float2bfloat16(v);
}

// ---------------- persistent encoder ----------------
// grid (32 m, 16 n), 256 threads (4 waves). Block tile 32 rows x 128 gate-cols.
// Wave tile 32x32 (2m x 2n 16x16 frags): breg[2][18] = 144 VGPR.
// 2 blocks/CU (39.6 KB LDS, launch_bounds(256,2)).
__global__ __launch_bounds__(256, 2) void enc_persist(
    const __hip_bfloat16* __restrict__ Xb,
    __hip_bfloat16* __restrict__ h0buf, __hip_bfloat16* __restrict__ h1buf,
    float* __restrict__ cenc,
    const __hip_bfloat16* __restrict__ Wp, const float* __restrict__ bp,
    const float* __restrict__ pi, const float* __restrict__ pf, const float* __restrict__ po,
    int* __restrict__ wrflag)
{
    __shared__ __align__(16) unsigned short Alds[32][584]; // 37376 B, bank-delta 4
    __shared__ __align__(16) unsigned short Hlds[32][36];  // 2304 B, 8B-aligned rows

    const int tid  = threadIdx.x;
    const int lane = tid & 63;
    const int wv   = tid >> 6;     // 0..3
    const int bm   = blockIdx.x;   // 0..31
    const int bn   = blockIdx.y;   // 0..15
    const int m0   = bm * 32;
    const int lr   = lane & 15;
    const int q    = lane >> 4;    // 0..3
    const int lk   = q * 8;

    // persistent weight fragments: cols bn*128 + wv*32 + ni*16 + lr
    bf16x8 breg[2][18];
    #pragma unroll
    for (int ni = 0; ni < 2; ++ni) {
        const __hip_bfloat16* wb = Wp + (size_t)(bn * 128 + wv * 32 + ni * 16 + lr) * KENC + lk;
        #pragma unroll
        for (int i = 0; i < 18; ++i)
            breg[ni][i] = *reinterpret_cast<const bf16x8*>(wb + i * 32);
    }

    // per-lane epilogue params
    const int u = lr >> 2;
    const int e = lane & 3;
    float4 bb[2];
    float ppi[2], ppf[2], ppo[2];
    int jl[2];
    #pragma unroll
    for (int ni = 0; ni < 2; ++ni) {
        jl[ni] = wv * 8 + ni * 4 + u;
        int jg = bn * 32 + jl[ni];
        bb[ni] = *reinterpret_cast<const float4*>(bp + 4 * jg);
        ppi[ni] = pi[jg]; ppf[ni] = pf[jg]; ppo[ni] = po[jg];
    }

    float creg[2][2] = {{0.f, 0.f}, {0.f, 0.f}};
    __hip_bfloat16* hbuf[2] = {h0buf, h1buf};

    for (int t = 0; t < ND; ++t) {
        // stage x-part (independent of h_t) before the spin
        {
            int row = tid >> 3, ch = tid & 7;
            *reinterpret_cast<bf16x8*>(&Alds[row][ch * 8]) =
                *reinterpret_cast<const bf16x8*>(Xb + ((size_t)t * NB + m0 + row) * NI + ch * 8);
        }
        if (t > 0 && tid == 0) {
            spin_ge(&wrflag[bm * ND + (t - 1)], 16);
            __builtin_amdgcn_fence(__ATOMIC_ACQUIRE, "agent");
        }
        __syncthreads();
        const __hip_bfloat16* hsrc = hbuf[t & 1];
        #pragma unroll
        for (int it = 0; it < 8; ++it) {
            int idx = tid + it * 256;
            int row = idx >> 6, ch = idx & 63;
            *reinterpret_cast<bf16x8*>(&Alds[row][64 + ch * 8]) =
                *reinterpret_cast<const bf16x8*>(hsrc + (size_t)(m0 + row) * NHE + ch * 8);
        }
        __syncthreads();

        // K-loop: 18 chunks, 2 A-frag reads + 4 MFMAs per chunk
        f32x4 acc[2][2];
        #pragma unroll
        for (int mi = 0; mi < 2; ++mi)
            #pragma unroll
            for (int ni = 0; ni < 2; ++ni) acc[mi][ni] = {0.f, 0.f, 0.f, 0.f};
        #pragma unroll
        for (int i = 0; i < 18; ++i) {
            bf16x8 a[2];
            #pragma unroll
            for (int mi = 0; mi < 2; ++mi)
                a[mi] = *reinterpret_cast<const bf16x8*>(&Alds[16 * mi + lr][i * 32 + lk]);
            #pragma unroll
            for (int mi = 0; mi < 2; ++mi)
                #pragma unroll
                for (int ni = 0; ni < 2; ++ni)
                    acc[mi][ni] = mfma16(a[mi], breg[ni][i], acc[mi][ni]);
        }

        // epilogue: in-register peephole update, h -> Hlds
        #pragma unroll
        for (int mi = 0; mi < 2; ++mi) {
            #pragma unroll
            for (int ni = 0; ni < 2; ++ni) {
                float z0, z1, z2, z3;
                quadtr(acc[mi][ni], lane, z0, z1, z2, z3);
                float c_old = creg[mi][ni];
                float gi = sigmf(z0 + bb[ni].x + ppi[ni] * c_old);
                float gf = sigmf(z1 + bb[ni].y + ppf[ni] * c_old);
                float cn = gf * c_old + gi * tanh_f(z2 + bb[ni].z);
                float go = sigmf(z3 + bb[ni].w + ppo[ni] * cn);
                creg[mi][ni] = cn;
                int row = 16 * mi + 4 * q + e;
                __hip_bfloat16 hv = __float2bfloat16(go * tanh_f(cn));
                Hlds[row][jl[ni]] = reinterpret_cast<unsigned short&>(hv);
                if (t == ND - 1)
                    cenc[(size_t)(m0 + row) * NHE + bn * 32 + jl[ni]] = cn;
            }
        }
        __syncthreads();

        if (t < ND - 1) {
            // coalesced h store: 32 rows x 64 B
            {
                int row = tid >> 3, k8 = tid & 7;
                __hip_bfloat16* hdst = hbuf[(t + 1) & 1];
                *reinterpret_cast<uint2*>(hdst + (size_t)(m0 + row) * NHE + bn * 32 + k8 * 4) =
                    *reinterpret_cast<const uint2*>(&Hlds[row][k8 * 4]);
            }
            __syncthreads();  // all waves' stores drained (vmcnt(0) at barrier)
            if (tid == 0)
                __hip_atomic_fetch_add(&wrflag[bm * ND + t], 1,
                                       __ATOMIC_RELEASE, __HIP_MEMORY_SCOPE_AGENT);
        }
    }
}

// ---------------- persistent decoder (+ fused projection) ----------------
// grid (32 m, 9 n): bn 0..7 gate blocks (tile 32x128), bn==8 projection (32x64).
__global__ __launch_bounds__(256, 2) void dec_persist(
    __hip_bfloat16* __restrict__ hd0, __hip_bfloat16* __restrict__ hd1,
    const float* __restrict__ zdec,
    const __hip_bfloat16* __restrict__ Wp, const float* __restrict__ bp,
    const float* __restrict__ pi, const float* __restrict__ pf, const float* __restrict__ po,
    const float* __restrict__ ob,
    float* __restrict__ ox, float* __restrict__ oxr,
    int* __restrict__ wr2, int* __restrict__ prd)
{
    __shared__ __align__(16) unsigned short Alds[32][264]; // 16896 B
    __shared__ __align__(16) unsigned short Hlds[32][36];

    const int tid  = threadIdx.x;
    const int lane = tid & 63;
    const int wv   = tid >> 6;
    const int bm   = blockIdx.x;   // 0..31
    const int bn   = blockIdx.y;   // 0..8
    const int m0   = bm * 32;
    const int lr   = lane & 15;
    const int q    = lane >> 4;
    const int lk   = q * 8;

    __hip_bfloat16* hbuf[2] = {hd0, hd1};

    if (bn < 8) {
        // ---- gate blocks ----
        bf16x8 breg[2][8];
        #pragma unroll
        for (int ni = 0; ni < 2; ++ni) {
            const __hip_bfloat16* wb = Wp + (size_t)(bn * 128 + wv * 32 + ni * 16 + lr) * KDEC + lk;
            #pragma unroll
            for (int i = 0; i < 8; ++i)
                breg[ni][i] = *reinterpret_cast<const bf16x8*>(wb + i * 32);
        }

        const int u = lr >> 2;
        const int e = lane & 3;
        float4 bb[2];
        float ppi[2], ppf[2], ppo[2];
        int jl[2];
        #pragma unroll
        for (int ni = 0; ni < 2; ++ni) {
            jl[ni] = wv * 8 + ni * 4 + u;
            int jg = bn * 32 + jl[ni];
            bb[ni] = *reinterpret_cast<const float4*>(bp + 4 * jg);
            ppi[ni] = pi[jg]; ppf[ni] = pf[jg]; ppo[ni] = po[jg];
        }

        float creg[2][2];
        #pragma unroll
        for (int mi = 0; mi < 2; ++mi)
            #pragma unroll
            for (int ni = 0; ni < 2; ++ni)
                creg[mi][ni] = zdec[(size_t)(m0 + 16 * mi + 4 * q + e) * NH + bn * 32 + jl[ni]];

        for (int t = 0; t < ND; ++t) {
            if (tid == 0) {
                if (t >= 1) spin_ge(&wr2[bm * ND + (t - 1)], 8);
                if (t >= 2) spin_ge(&prd[bm * ND + (t - 2)], 1);
                if (t >= 1) __builtin_amdgcn_fence(__ATOMIC_ACQUIRE, "agent");
            }
            __syncthreads();
            const __hip_bfloat16* hsrc = hbuf[t & 1];
            #pragma unroll
            for (int it = 0; it < 4; ++it) {
                int idx = tid + it * 256;
                int row = idx >> 5, ch = idx & 31;
                *reinterpret_cast<bf16x8*>(&Alds[row][ch * 8]) =
                    *reinterpret_cast<const bf16x8*>(hsrc + (size_t)(m0 + row) * NH + ch * 8);
            }
            __syncthreads();

            f32x4 acc[2][2];
            #pragma unroll
            for (int mi = 0; mi < 2; ++mi)
                #pragma unroll
                for (int ni = 0; ni < 2; ++ni) acc[mi][ni] = {0.f, 0.f, 0.f, 0.f};
            #pragma unroll
            for (int i = 0; i < 8; ++i) {
                bf16x8 a[2];
                #pragma unroll
                for (int mi = 0; mi < 2; ++mi)
                    a[mi] = *reinterpret_cast<const bf16x8*>(&Alds[16 * mi + lr][i * 32 + lk]);
                #pragma unroll
                for (int mi = 0; mi < 2; ++mi)
                    #pragma unroll
                    for (int ni = 0; ni < 2; ++ni)
                        acc[mi][ni] = mfma16(a[mi], breg[ni][i], acc[mi][ni]);
            }

            #pragma unroll
            for (int mi = 0; mi < 2; ++mi) {
                #pragma unroll
                for (int ni = 0; ni < 2; ++ni) {
                    float z0, z1, z2, z3;
                    quadtr(acc[mi][ni], lane, z0, z1, z2, z3);
                    float c_old = creg[mi][ni];
                    float gi = sigmf(z0 + bb[ni].x + ppi[ni] * c_old);
                    float gf = sigmf(z1 + bb[ni].y + ppf[ni] * c_old);
                    float cn = gf * c_old + gi * tanh_f(z2 + bb[ni].z);
                    float go = sigmf(z3 + bb[ni].w + ppo[ni] * cn);
                    creg[mi][ni] = cn;
                    int row = 16 * mi + 4 * q + e;
                    __hip_bfloat16 hv = __float2bfloat16(go * tanh_f(cn));
                    Hlds[row][jl[ni]] = reinterpret_cast<unsigned short&>(hv);
                }
            }
            __syncthreads();

            {
                int row = tid >> 3, k8 = tid & 7;
                __hip_bfloat16* hdst = hbuf[(t + 1) & 1];
                *reinterpret_cast<uint2*>(hdst + (size_t)(m0 + row) * NH + bn * 32 + k8 * 4) =
                    *reinterpret_cast<const uint2*>(&Hlds[row][k8 * 4]);
            }
            __syncthreads();
            if (tid == 0)
                __hip_atomic_fetch_add(&wr2[bm * ND + t], 1,
                                       __ATOMIC_RELEASE, __HIP_MEMORY_SCOPE_AGENT);
        }
    } else {
        // ---- projection block: x_raw[:, s, :] = h_{s+1} @ ow + ob ----
        bf16x8 breg[8];
        const __hip_bfloat16* wb = Wp + (size_t)(1024 + wv * 16 + lr) * KDEC + lk;
        #pragma unroll
        for (int i = 0; i < 8; ++i)
            breg[i] = *reinterpret_cast<const bf16x8*>(wb + i * 32);
        const float obv = ob[wv * 16 + lr];

        for (int s = 0; s < ND; ++s) {
            if (tid == 0) {
                spin_ge(&wr2[bm * ND + s], 8);
                __builtin_amdgcn_fence(__ATOMIC_ACQUIRE, "agent");
            }
            __syncthreads();
            const __hip_bfloat16* hsrc = hbuf[(s + 1) & 1];
            #pragma unroll
            for (int it = 0; it < 4; ++it) {
                int idx = tid + it * 256;
                int row = idx >> 5, ch = idx & 31;
                *reinterpret_cast<bf16x8*>(&Alds[row][ch * 8]) =
                    *reinterpret_cast<const bf16x8*>(hsrc + (size_t)(m0 + row) * NH + ch * 8);
            }
            __syncthreads();
            // h copied to LDS -> gates may overwrite the buffer
            if (tid == 0)
                __hip_atomic_fetch_add(&prd[bm * ND + s], 1,
                                       __ATOMIC_RELEASE, __HIP_MEMORY_SCOPE_AGENT);

            f32x4 acc[2];
            #pragma unroll
            for (int mi = 0; mi < 2; ++mi) acc[mi] = {0.f, 0.f, 0.f, 0.f};
            #pragma unroll
            for (int i = 0; i < 8; ++i) {
                bf16x8 a[2];
                #pragma unroll
                for (int mi = 0; mi < 2; ++mi)
                    a[mi] = *reinterpret_cast<const bf16x8*>(&Alds[16 * mi + lr][i * 32 + lk]);
                #pragma unroll
                for (int mi = 0; mi < 2; ++mi)
                    acc[mi] = mfma16(a[mi], breg[i], acc[mi]);
            }

            int colp = wv * 16 + lr;
            #pragma unroll
            for (int mi = 0; mi < 2; ++mi) {
                #pragma unroll
                for (int v = 0; v < 4; ++v) {
                    int row = m0 + 16 * mi + 4 * q + v;
                    float val = acc[mi][v] + obv;
                    size_t off = (size_t)row * (ND * NI) + (size_t)s * NI + colp;
                    oxr[off] = val;
                    ox[off]  = sigmf(val);
                }
            }
        }
    }
}

// ---------------- middle: z = mu + exp(0.5*ls)*noise ----------------
__global__ void mid_kernel(const float* __restrict__ cenc, const float* __restrict__ noise,
                           float* __restrict__ zdec, float* __restrict__ oz,
                           float* __restrict__ omut, float* __restrict__ olst)
{
    int idx = blockIdx.x * 256 + threadIdx.x;  // < 262144
    int b = idx >> 8, h = idx & 255;
    float mu = cenc[b * NHE + h];
    float ls = cenc[b * NHE + NH + h];
    float zz = mu + expf(0.5f * ls) * noise[idx];
    omut[idx] = mu;
    olst[idx] = ls;
    oz[idx]   = zz;
    zdec[idx] = zz;
}

// ---------------- mixture params ----------------
__global__ void mix_kernel(const float* __restrict__ mu_in, const float* __restrict__ s2_in,
                           const float* __restrict__ phi_in,
                           float* __restrict__ mu_out, float* __restrict__ s2_out,
                           float* __restrict__ phi_out)
{
    int idx = blockIdx.x * 256 + threadIdx.x;  // < 2048
    mu_out[idx] = mu_in[idx];
    float x = s2_in[idx];
    s2_out[idx] = (x > 20.0f) ? x : log1pf(expf(x));
    if (idx == 0) {
        float m = phi_in[0];
        for (int k = 1; k < 8; ++k) m = fmaxf(m, phi_in[k]);
        float e[8], s = 0.0f;
        for (int k = 0; k < 8; ++k) { e[k] = expf(phi_in[k] - m); s += e[k]; }
        for (int k = 0; k < 8; ++k) phi_out[k] = e[k] / s;
    }
}

// ---------------- host ----------------
extern "C" void kernel_launch(void* const* d_in, const int* in_sizes, int n_in,
                              void* d_out, int out_size, void* d_ws, size_t ws_size,
                              hipStream_t stream)
{
    const float* X     = (const float*)d_in[0];
    const int*   W     = (const int*)d_in[1];
    const float* noise = (const float*)d_in[2];
    const float* A     = (const float*)d_in[3];
    const float* eWx   = (const float*)d_in[4];
    const float* eWh   = (const float*)d_in[5];
    const float* eb    = (const float*)d_in[6];
    const float* epi   = (const float*)d_in[7];
    const float* epf   = (const float*)d_in[8];
    const float* epo   = (const float*)d_in[9];
    const float* dWh   = (const float*)d_in[11];
    const float* db    = (const float*)d_in[12];
    const float* dpi   = (const float*)d_in[13];
    const float* dpf   = (const float*)d_in[14];
    const float* dpo   = (const float*)d_in[15];
    const float* ow    = (const float*)d_in[16];
    const float* ob    = (const float*)d_in[17];
    const float* muc   = (const float*)d_in[18];
    const float* s2c   = (const float*)d_in[19];
    const float* phic  = (const float*)d_in[20];

    float* out = (float*)d_out;
    float* o_x    = out;
    float* o_xraw = out + 8388608;
    float* o_muc  = out + 16777216;
    float* o_s2c  = out + 16779264;
    float* o_phic = out + 16781312;
    float* o_z    = out + 16781320;
    float* o_mut  = out + 17043464;
    float* o_lst  = out + 17305608;

    char* ws = (char*)d_ws;
    __hip_bfloat16* Wencp = (__hip_bfloat16*)(ws + 0);          // 2359296
    __hip_bfloat16* Wdecp = (__hip_bfloat16*)(ws + 2359296);    // 589824
    float*          bencp = (float*)(ws + 2949120);             // 8192
    float*          bdecp = (float*)(ws + 2957312);             // 8192
    __hip_bfloat16* Xb    = (__hip_bfloat16*)(ws + 2965504);    // 16777216
    __hip_bfloat16* he0   = (__hip_bfloat16*)(ws + 19742720);   // 1048576
    __hip_bfloat16* he1   = (__hip_bfloat16*)(ws + 20791296);   // 1048576
    float*          cenc  = (float*)(ws + 21839872);            // 2097152
    __hip_bfloat16* hd0   = (__hip_bfloat16*)(ws + 23937024);   // 524288
    __hip_bfloat16* hd1   = (__hip_bfloat16*)(ws + 24461312);   // 524288
    float*          zdec  = (float*)(ws + 24985600);            // 1048576
    int*            encwr = (int*)(ws + 26034176);              // 16384
    int*            decwr = (int*)(ws + 26050560);              // 16384
    int*            decpr = (int*)(ws + 26066944);              // 16384 (end 26083328)

    hipMemsetAsync(he0, 0, 1048576, stream);
    hipMemsetAsync(hd0, 0, 524288, stream);
    hipMemsetAsync(encwr, 0, 49152, stream);  // encwr+decwr+decpr contiguous

    pack_enc_kernel<<<dim3(3, 2048), 256, 0, stream>>>(eWx, eWh, eb, Wencp, bencp);
    pack_dec_kernel<<<dim3(1, 1152), 256, 0, stream>>>(dWh, ow, db, Wdecp, bdecp);
    pack_xb_kernel<<<32768, 256, 0, stream>>>(X, W, A, Xb);

    enc_persist<<<dim3(32, 16), 256, 0, stream>>>(
        Xb, he0, he1, cenc, Wencp, bencp, epi, epf, epo, encwr);

    mid_kernel<<<1024, 256, 0, stream>>>(cenc, noise, zdec, o_z, o_mut, o_lst);
    mix_kernel<<<8, 256, 0, stream>>>(muc, s2c, phic, o_muc, o_s2c, o_phic);

    dec_persist<<<dim3(32, 9), 256, 0, stream>>>(
        hd0, hd1, zdec, Wdecp, bdecp, dpi, dpf, dpo, ob, o_x, o_xraw, decwr, decpr);
}

// Round 4
// 1804.778 us; speedup vs baseline: 1.8052x; 1.8052x over previous
//
#include <hip/hip_runtime.h>
#include <hip/hip_bf16.h>

typedef __attribute__((ext_vector_type(4))) float f32x4;
typedef __attribute__((ext_vector_type(8))) short bf16x8;

#define NB 1024   // batch
#define ND 128    // time steps
#define NI 64     // input dim
#define NH 256    // dec hidden
#define NHE 512   // enc hidden
#define KENC 576  // NI + NHE
#define NENC 2048 // 4*NHE
#define KDEC 256
#define ESTR 648  // enc A-tile stride: 8*81 (81 odd -> conflict-free b128 rows)
#define DSTR 264  // dec A-tile stride: 8*33

__device__ __forceinline__ float sigmf(float x) { return 1.0f / (1.0f + __expf(-x)); }
__device__ __forceinline__ float tanh_f(float x) { return 1.0f - 2.0f / (__expf(2.0f * x) + 1.0f); }

__device__ __forceinline__ f32x4 mfma16(bf16x8 a, bf16x8 b, f32x4 c) {
    return __builtin_amdgcn_mfma_f32_16x16x32_bf16(a, b, c, 0, 0, 0);
}

// device-scope coherent (LLC write-through / LLC read) 8B accesses
__device__ __forceinline__ void st_ull(unsigned long long* p, unsigned long long v) {
    __hip_atomic_store(p, v, __ATOMIC_RELAXED, __HIP_MEMORY_SCOPE_AGENT);
}
__device__ __forceinline__ unsigned long long ld_ull(const unsigned long long* p) {
    return __hip_atomic_load(p, __ATOMIC_RELAXED, __HIP_MEMORY_SCOPE_AGENT);
}

__device__ __forceinline__ void spin_ge(const int* p, int target) {
    int g = 0;
    while (__hip_atomic_load(p, __ATOMIC_RELAXED, __HIP_MEMORY_SCOPE_AGENT) < target) {
        __builtin_amdgcn_s_sleep(2);
        if (++g > (1 << 20)) break;   // deadlock bailout -> visible failure, no hang
    }
}

// 4x4 transpose within each lane-quad across regs v0..v3. (verified rounds 1-3)
__device__ __forceinline__ void quadtr(f32x4 a, int lane,
                                       float& z0, float& z1, float& z2, float& z3) {
    float x0 = a[0], x1 = a[1], x2 = a[2], x3 = a[3];
    float s0 = __shfl_xor(x0, 1), s1 = __shfl_xor(x1, 1),
          s2 = __shfl_xor(x2, 1), s3 = __shfl_xor(x3, 1);
    bool o1 = (lane & 1) != 0;
    float y0 = o1 ? s1 : x0;
    float y1 = o1 ? x1 : s0;
    float y2 = o1 ? s3 : x2;
    float y3 = o1 ? x3 : s2;
    float t0 = __shfl_xor(y0, 2), t1 = __shfl_xor(y1, 2),
          t2 = __shfl_xor(y2, 2), t3 = __shfl_xor(y3, 2);
    bool o2 = (lane & 2) != 0;
    z0 = o2 ? t2 : y0;
    z1 = o2 ? t3 : y1;
    z2 = o2 ? y2 : t0;
    z3 = o2 ? y3 : t1;
}

// ---------------- packing kernels (unchanged, verified) ----------------

__global__ void pack_enc_kernel(const float* __restrict__ Wx, const float* __restrict__ Wh,
                                const float* __restrict__ bsrc,
                                __hip_bfloat16* __restrict__ Wp, float* __restrict__ bp)
{
    int n = blockIdx.y;
    int k = blockIdx.x * 256 + threadIdx.x;
    int j = n >> 2, g = n & 3;
    int col = g * NHE + j;
    if (k < KENC) {
        float v = (k < NI) ? Wx[k * NENC + col] : Wh[(k - NI) * NENC + col];
        Wp[(size_t)n * KENC + k] = __float2bfloat16(v);
    }
    if (blockIdx.x == 0 && threadIdx.x == 0) bp[n] = bsrc[col];
}

__global__ void pack_dec_kernel(const float* __restrict__ Wh, const float* __restrict__ ow,
                                const float* __restrict__ bsrc,
                                __hip_bfloat16* __restrict__ Wp, float* __restrict__ bp)
{
    int n = blockIdx.y;          // 0..1151
    int k = threadIdx.x;         // 0..255
    float v;
    if (n < 1024) {
        int j = n >> 2, g = n & 3;
        int col = g * NH + j;
        v = Wh[k * 1024 + col];
        if (k == 0) bp[n] = bsrc[col];
    } else if (n < 1088) {
        v = ow[k * NI + (n - 1024)];
    } else {
        v = 0.0f;
    }
    Wp[(size_t)n * KDEC + k] = __float2bfloat16(v);
}

__global__ void pack_xb_kernel(const float* __restrict__ X, const int* __restrict__ W,
                               const float* __restrict__ A, __hip_bfloat16* __restrict__ Xb)
{
    int idx = blockIdx.x * 256 + threadIdx.x;
    int i = idx & 63;
    int t1 = idx >> 6;
    int b = t1 & 1023;
    int d = t1 >> 10;
    int src = (b * ND + d) * NI + i;
    float v = W[src] ? X[src] : A[d * NI + i];
    Xb[idx] = __float2bfloat16(v);
}

// ---------------- persistent encoder ----------------
// grid (16 m, 16 n), 512 threads (8 waves). Block tile 64 rows x 128 gate-cols.
// Wave tile 64x16 (breg[18] = 72 VGPR). Weights in regs all 128 steps; c in regs.
// h exchange through LLC via relaxed device-scope atomics; NO fences.
__global__ __launch_bounds__(512, 2) void enc_persist(
    const __hip_bfloat16* __restrict__ Xb,
    __hip_bfloat16* __restrict__ h0buf, __hip_bfloat16* __restrict__ h1buf,
    float* __restrict__ cenc,
    const __hip_bfloat16* __restrict__ Wp, const float* __restrict__ bp,
    const float* __restrict__ pi, const float* __restrict__ pf, const float* __restrict__ po,
    int* __restrict__ wrflag)
{
    __shared__ __align__(16) unsigned short Alds[64][ESTR]; // 82944 B
    __shared__ __align__(16) unsigned short Hlds[64][36];   // 4608 B

    const int tid  = threadIdx.x;
    const int lane = tid & 63;
    const int wv   = tid >> 6;     // 0..7
    const int bm   = blockIdx.x;   // 0..15
    const int bn   = blockIdx.y;   // 0..15
    const int m0   = bm * 64;
    const int lr   = lane & 15;
    const int q    = lane >> 4;    // 0..3
    const int lk   = q * 8;

    // persistent weight fragments: col = bn*128 + wv*16 + lr
    const int col = bn * 128 + wv * 16 + lr;
    bf16x8 breg[18];
    #pragma unroll
    for (int i = 0; i < 18; ++i)
        breg[i] = *reinterpret_cast<const bf16x8*>(Wp + (size_t)col * KENC + i * 32 + lk);

    // per-lane epilogue params: unit j (local ju), bias, peepholes
    const int u  = (lane >> 2) & 3;
    const int e  = lane & 3;
    const int ju = wv * 4 + u;            // local unit 0..31
    const int j  = bn * 32 + ju;          // global unit
    const float4 bb = *reinterpret_cast<const float4*>(bp + 4 * j);
    const float ppi = pi[j], ppf = pf[j], ppo = po[j];
    const int rowb = 4 * q + e;           // local row base 0..15

    float creg[4] = {0.f, 0.f, 0.f, 0.f};
    __hip_bfloat16* hbuf[2] = {h0buf, h1buf};

    for (int t = 0; t < ND; ++t) {
        // stage x-part (independent of h_t) before the spin
        {
            int row = tid >> 3, ch = tid & 7;
            *reinterpret_cast<bf16x8*>(&Alds[row][ch * 8]) =
                *reinterpret_cast<const bf16x8*>(Xb + ((size_t)t * NB + m0 + row) * NI + ch * 8);
        }
        if (t > 0 && tid == 0) spin_ge(&wrflag[bm * ND + (t - 1)], 16);
        __syncthreads();

        // stage h via coherent 8B loads (LLC): 64 rows x 512 cols = 8192 ULLs
        {
            const unsigned long long* hsrc =
                (const unsigned long long*)(hbuf[t & 1] + (size_t)m0 * NHE);
            #pragma unroll
            for (int it = 0; it < 16; ++it) {
                int idx = tid + it * 512;
                int row = idx >> 7, c8 = idx & 127;
                unsigned long long v = ld_ull(hsrc + (size_t)row * 128 + c8);
                *reinterpret_cast<unsigned long long*>(&Alds[row][64 + c8 * 4]) = v;
            }
        }
        __syncthreads();

        // K-loop: 18 chunks, 4 A-frag reads + 4 MFMAs per chunk
        f32x4 acc[4];
        #pragma unroll
        for (int mi = 0; mi < 4; ++mi) acc[mi] = {0.f, 0.f, 0.f, 0.f};
        #pragma unroll
        for (int i = 0; i < 18; ++i) {
            bf16x8 a[4];
            #pragma unroll
            for (int mi = 0; mi < 4; ++mi)
                a[mi] = *reinterpret_cast<const bf16x8*>(&Alds[16 * mi + lr][i * 32 + lk]);
            #pragma unroll
            for (int mi = 0; mi < 4; ++mi)
                acc[mi] = mfma16(a[mi], breg[i], acc[mi]);
        }

        // epilogue: in-register peephole update -> Hlds
        #pragma unroll
        for (int mi = 0; mi < 4; ++mi) {
            float z0, z1, z2, z3;
            quadtr(acc[mi], lane, z0, z1, z2, z3);
            float c_old = creg[mi];
            float gi = sigmf(z0 + bb.x + ppi * c_old);
            float gf = sigmf(z1 + bb.y + ppf * c_old);
            float cn = gf * c_old + gi * tanh_f(z2 + bb.z);
            float go = sigmf(z3 + bb.w + ppo * cn);
            creg[mi] = cn;
            int row = 16 * mi + rowb;
            __hip_bfloat16 hv = __float2bfloat16(go * tanh_f(cn));
            Hlds[row][ju] = reinterpret_cast<unsigned short&>(hv);
            if (t == ND - 1) cenc[(size_t)(m0 + row) * NHE + j] = cn;
        }
        __syncthreads();

        if (t < ND - 1) {
            // coalesced coherent h store: 64 rows x 64 B
            {
                int row = tid >> 3, k8 = tid & 7;
                __hip_bfloat16* hdst = hbuf[(t + 1) & 1];
                unsigned long long v =
                    *reinterpret_cast<const unsigned long long*>(&Hlds[row][k8 * 4]);
                st_ull((unsigned long long*)(hdst + (size_t)(m0 + row) * NHE + bn * 32 + k8 * 4), v);
            }
            __syncthreads();  // each wave drains vmcnt(0) -> stores LLC-acked
            if (tid == 0)
                __hip_atomic_fetch_add(&wrflag[bm * ND + t], 1,
                                       __ATOMIC_RELAXED, __HIP_MEMORY_SCOPE_AGENT);
        }
    }
}

// ---------------- persistent decoder (+ fused projection) ----------------
// grid (16 m, 9 n): bn 0..7 gate blocks (64x128), bn==8 projection (64x64, waves 0-3).
__global__ __launch_bounds__(512, 2) void dec_persist(
    __hip_bfloat16* __restrict__ hd0, __hip_bfloat16* __restrict__ hd1,
    const float* __restrict__ zdec,
    const __hip_bfloat16* __restrict__ Wp, const float* __restrict__ bp,
    const float* __restrict__ pi, const float* __restrict__ pf, const float* __restrict__ po,
    const float* __restrict__ ob,
    float* __restrict__ ox, float* __restrict__ oxr,
    int* __restrict__ wr2, int* __restrict__ prd)
{
    __shared__ __align__(16) unsigned short Alds[64][DSTR]; // 33792 B
    __shared__ __align__(16) unsigned short Hlds[64][36];

    const int tid  = threadIdx.x;
    const int lane = tid & 63;
    const int wv   = tid >> 6;
    const int bm   = blockIdx.x;   // 0..15
    const int bn   = blockIdx.y;   // 0..8
    const int m0   = bm * 64;
    const int lr   = lane & 15;
    const int q    = lane >> 4;
    const int lk   = q * 8;

    __hip_bfloat16* hbuf[2] = {hd0, hd1};

    if (bn < 8) {
        // ---- gate blocks ----
        const int col = bn * 128 + wv * 16 + lr;
        bf16x8 breg[8];
        #pragma unroll
        for (int i = 0; i < 8; ++i)
            breg[i] = *reinterpret_cast<const bf16x8*>(Wp + (size_t)col * KDEC + i * 32 + lk);

        const int u  = (lane >> 2) & 3;
        const int e  = lane & 3;
        const int ju = wv * 4 + u;
        const int j  = bn * 32 + ju;
        const float4 bb = *reinterpret_cast<const float4*>(bp + 4 * j);
        const float ppi = pi[j], ppf = pf[j], ppo = po[j];
        const int rowb = 4 * q + e;

        float creg[4];
        #pragma unroll
        for (int mi = 0; mi < 4; ++mi)
            creg[mi] = zdec[(size_t)(m0 + 16 * mi + rowb) * NH + j];

        for (int t = 0; t < ND; ++t) {
            if (tid == 0) {
                if (t >= 1) spin_ge(&wr2[bm * ND + (t - 1)], 8);
                if (t >= 2) spin_ge(&prd[bm * ND + (t - 2)], 1);
            }
            __syncthreads();

            // stage h: 64 rows x 256 cols = 4096 ULLs
            {
                const unsigned long long* hsrc =
                    (const unsigned long long*)(hbuf[t & 1] + (size_t)m0 * NH);
                #pragma unroll
                for (int it = 0; it < 8; ++it) {
                    int idx = tid + it * 512;
                    int row = idx >> 6, c8 = idx & 63;
                    unsigned long long v = ld_ull(hsrc + (size_t)row * 64 + c8);
                    *reinterpret_cast<unsigned long long*>(&Alds[row][c8 * 4]) = v;
                }
            }
            __syncthreads();

            f32x4 acc[4];
            #pragma unroll
            for (int mi = 0; mi < 4; ++mi) acc[mi] = {0.f, 0.f, 0.f, 0.f};
            #pragma unroll
            for (int i = 0; i < 8; ++i) {
                bf16x8 a[4];
                #pragma unroll
                for (int mi = 0; mi < 4; ++mi)
                    a[mi] = *reinterpret_cast<const bf16x8*>(&Alds[16 * mi + lr][i * 32 + lk]);
                #pragma unroll
                for (int mi = 0; mi < 4; ++mi)
                    acc[mi] = mfma16(a[mi], breg[i], acc[mi]);
            }

            #pragma unroll
            for (int mi = 0; mi < 4; ++mi) {
                float z0, z1, z2, z3;
                quadtr(acc[mi], lane, z0, z1, z2, z3);
                float c_old = creg[mi];
                float gi = sigmf(z0 + bb.x + ppi * c_old);
                float gf = sigmf(z1 + bb.y + ppf * c_old);
                float cn = gf * c_old + gi * tanh_f(z2 + bb.z);
                float go = sigmf(z3 + bb.w + ppo * cn);
                creg[mi] = cn;
                int row = 16 * mi + rowb;
                __hip_bfloat16 hv = __float2bfloat16(go * tanh_f(cn));
                Hlds[row][ju] = reinterpret_cast<unsigned short&>(hv);
            }
            __syncthreads();

            {
                int row = tid >> 3, k8 = tid & 7;
                __hip_bfloat16* hdst = hbuf[(t + 1) & 1];
                unsigned long long v =
                    *reinterpret_cast<const unsigned long long*>(&Hlds[row][k8 * 4]);
                st_ull((unsigned long long*)(hdst + (size_t)(m0 + row) * NH + bn * 32 + k8 * 4), v);
            }
            __syncthreads();
            if (tid == 0)
                __hip_atomic_fetch_add(&wr2[bm * ND + t], 1,
                                       __ATOMIC_RELAXED, __HIP_MEMORY_SCOPE_AGENT);
        }
    } else {
        // ---- projection block: x_raw[:, s, :] = h_{s+1} @ ow + ob ----
        bf16x8 breg[8];
        const __hip_bfloat16* wb = Wp + (size_t)(1024 + wv * 16 + lr) * KDEC + lk;
        #pragma unroll
        for (int i = 0; i < 8; ++i)
            breg[i] = *reinterpret_cast<const bf16x8*>(wb + i * 32);
        const float obv = ob[(wv & 3) * 16 + lr];

        for (int s = 0; s < ND; ++s) {
            if (tid == 0) spin_ge(&wr2[bm * ND + s], 8);
            __syncthreads();

            {
                const unsigned long long* hsrc =
                    (const unsigned long long*)(hbuf[(s + 1) & 1] + (size_t)m0 * NH);
                #pragma unroll
                for (int it = 0; it < 8; ++it) {
                    int idx = tid + it * 512;
                    int row = idx >> 6, c8 = idx & 63;
                    unsigned long long v = ld_ull(hsrc + (size_t)row * 64 + c8);
                    *reinterpret_cast<unsigned long long*>(&Alds[row][c8 * 4]) = v;
                }
            }
            __syncthreads();
            // h copied to LDS -> gates may overwrite the buffer (loads drained at barrier)
            if (tid == 0)
                __hip_atomic_fetch_add(&prd[bm * ND + s], 1,
                                       __ATOMIC_RELAXED, __HIP_MEMORY_SCOPE_AGENT);

            if (wv < 4) {
                f32x4 acc[4];
                #pragma unroll
                for (int mi = 0; mi < 4; ++mi) acc[mi] = {0.f, 0.f, 0.f, 0.f};
                #pragma unroll
                for (int i = 0; i < 8; ++i) {
                    bf16x8 a[4];
                    #pragma unroll
                    for (int mi = 0; mi < 4; ++mi)
                        a[mi] = *reinterpret_cast<const bf16x8*>(&Alds[16 * mi + lr][i * 32 + lk]);
                    #pragma unroll
                    for (int mi = 0; mi < 4; ++mi)
                        acc[mi] = mfma16(a[mi], breg[i], acc[mi]);
                }
                int colp = wv * 16 + lr;
                #pragma unroll
                for (int mi = 0; mi < 4; ++mi) {
                    #pragma unroll
                    for (int v = 0; v < 4; ++v) {
                        int row = m0 + 16 * mi + 4 * q + v;
                        float val = acc[mi][v] + obv;
                        size_t off = (size_t)row * (ND * NI) + (size_t)s * NI + colp;
                        oxr[off] = val;
                        ox[off]  = sigmf(val);
                    }
                }
            }
        }
    }
}

// ---------------- middle: z = mu + exp(0.5*ls)*noise ----------------
__global__ void mid_kernel(const float* __restrict__ cenc, const float* __restrict__ noise,
                           float* __restrict__ zdec, float* __restrict__ oz,
                           float* __restrict__ omut, float* __restrict__ olst)
{
    int idx = blockIdx.x * 256 + threadIdx.x;  // < 262144
    int b = idx >> 8, h = idx & 255;
    float mu = cenc[b * NHE + h];
    float ls = cenc[b * NHE + NH + h];
    float zz = mu + expf(0.5f * ls) * noise[idx];
    omut[idx] = mu;
    olst[idx] = ls;
    oz[idx]   = zz;
    zdec[idx] = zz;
}

// ---------------- mixture params ----------------
__global__ void mix_kernel(const float* __restrict__ mu_in, const float* __restrict__ s2_in,
                           const float* __restrict__ phi_in,
                           float* __restrict__ mu_out, float* __restrict__ s2_out,
                           float* __restrict__ phi_out)
{
    int idx = blockIdx.x * 256 + threadIdx.x;  // < 2048
    mu_out[idx] = mu_in[idx];
    float x = s2_in[idx];
    s2_out[idx] = (x > 20.0f) ? x : log1pf(expf(x));
    if (idx == 0) {
        float m = phi_in[0];
        for (int k = 1; k < 8; ++k) m = fmaxf(m, phi_in[k]);
        float e[8], s = 0.0f;
        for (int k = 0; k < 8; ++k) { e[k] = expf(phi_in[k] - m); s += e[k]; }
        for (int k = 0; k < 8; ++k) phi_out[k] = e[k] / s;
    }
}

// ---------------- host ----------------
extern "C" void kernel_launch(void* const* d_in, const int* in_sizes, int n_in,
                              void* d_out, int out_size, void* d_ws, size_t ws_size,
                              hipStream_t stream)
{
    const float* X     = (const float*)d_in[0];
    const int*   W     = (const int*)d_in[1];
    const float* noise = (const float*)d_in[2];
    const float* A     = (const float*)d_in[3];
    const float* eWx   = (const float*)d_in[4];
    const float* eWh   = (const float*)d_in[5];
    const float* eb    = (const float*)d_in[6];
    const float* epi   = (const float*)d_in[7];
    const float* epf   = (const float*)d_in[8];
    const float* epo   = (const float*)d_in[9];
    const float* dWh   = (const float*)d_in[11];
    const float* db    = (const float*)d_in[12];
    const float* dpi   = (const float*)d_in[13];
    const float* dpf   = (const float*)d_in[14];
    const float* dpo   = (const float*)d_in[15];
    const float* ow    = (const float*)d_in[16];
    const float* ob    = (const float*)d_in[17];
    const float* muc   = (const float*)d_in[18];
    const float* s2c   = (const float*)d_in[19];
    const float* phic  = (const float*)d_in[20];

    float* out = (float*)d_out;
    float* o_x    = out;
    float* o_xraw = out + 8388608;
    float* o_muc  = out + 16777216;
    float* o_s2c  = out + 16779264;
    float* o_phic = out + 16781312;
    float* o_z    = out + 16781320;
    float* o_mut  = out + 17043464;
    float* o_lst  = out + 17305608;

    char* ws = (char*)d_ws;
    __hip_bfloat16* Wencp = (__hip_bfloat16*)(ws + 0);          // 2359296
    __hip_bfloat16* Wdecp = (__hip_bfloat16*)(ws + 2359296);    // 589824
    float*          bencp = (float*)(ws + 2949120);             // 8192
    float*          bdecp = (float*)(ws + 2957312);             // 8192
    __hip_bfloat16* Xb    = (__hip_bfloat16*)(ws + 2965504);    // 16777216
    __hip_bfloat16* he0   = (__hip_bfloat16*)(ws + 19742720);   // 1048576
    __hip_bfloat16* he1   = (__hip_bfloat16*)(ws + 20791296);   // 1048576
    float*          cenc  = (float*)(ws + 21839872);            // 2097152
    __hip_bfloat16* hd0   = (__hip_bfloat16*)(ws + 23937024);   // 524288
    __hip_bfloat16* hd1   = (__hip_bfloat16*)(ws + 24461312);   // 524288
    float*          zdec  = (float*)(ws + 24985600);            // 1048576
    int*            encwr = (int*)(ws + 26034176);              // 16384
    int*            decwr = (int*)(ws + 26050560);              // 16384
    int*            decpr = (int*)(ws + 26066944);              // 16384 (end 26083328)

    hipMemsetAsync(he0, 0, 1048576, stream);
    hipMemsetAsync(hd0, 0, 524288, stream);
    hipMemsetAsync(encwr, 0, 49152, stream);  // encwr+decwr+decpr contiguous

    pack_enc_kernel<<<dim3(3, 2048), 256, 0, stream>>>(eWx, eWh, eb, Wencp, bencp);
    pack_dec_kernel<<<dim3(1, 1152), 256, 0, stream>>>(dWh, ow, db, Wdecp, bdecp);
    pack_xb_kernel<<<32768, 256, 0, stream>>>(X, W, A, Xb);

    enc_persist<<<dim3(16, 16), 512, 0, stream>>>(
        Xb, he0, he1, cenc, Wencp, bencp, epi, epf, epo, encwr);

    mid_kernel<<<1024, 256, 0, stream>>>(cenc, noise, zdec, o_z, o_mut, o_lst);
    mix_kernel<<<8, 256, 0, stream>>>(muc, s2c, phic, o_muc, o_s2c, o_phic);

    dec_persist<<<dim3(16, 9), 512, 0, stream>>>(
        hd0, hd1, zdec, Wdecp, bdecp, dpi, dpf, dpo, ob, o_x, o_xraw, decwr, decpr);
}

// Round 6
// 1728.370 us; speedup vs baseline: 1.8850x; 1.0442x over previous
//
#include <hip/hip_runtime.h>
#include <hip/hip_bf16.h>

typedef __attribute__((ext_vector_type(4))) float f32x4;
typedef __attribute__((ext_vector_type(8))) short bf16x8;

#define NB 1024   // batch
#define ND 128    // time steps
#define NI 64     // input dim
#define NH 256    // dec hidden
#define NHE 512   // enc hidden
#define KENC 576  // NI + NHE
#define NENC 2048 // 4*NHE
#define KDEC 256
#define ESTR 584  // enc A-tile stride (elems): 8*73, 16B-aligned rows
#define DSTR 264  // dec A-tile stride: 8*33

__device__ __forceinline__ float sigmf(float x) { return 1.0f / (1.0f + __expf(-x)); }
__device__ __forceinline__ float tanh_f(float x) { return 1.0f - 2.0f / (__expf(2.0f * x) + 1.0f); }

__device__ __forceinline__ f32x4 mfma16(bf16x8 a, bf16x8 b, f32x4 c) {
    return __builtin_amdgcn_mfma_f32_16x16x32_bf16(a, b, c, 0, 0, 0);
}

// device-scope coherent (LLC write-through / LLC read) 8B accesses — verified r4
__device__ __forceinline__ void st_ull(unsigned long long* p, unsigned long long v) {
    __hip_atomic_store(p, v, __ATOMIC_RELAXED, __HIP_MEMORY_SCOPE_AGENT);
}
__device__ __forceinline__ unsigned long long ld_ull(const unsigned long long* p) {
    return __hip_atomic_load(p, __ATOMIC_RELAXED, __HIP_MEMORY_SCOPE_AGENT);
}

__device__ __forceinline__ void spin_ge(const int* p, int target) {
    int g = 0;
    while (__hip_atomic_load(p, __ATOMIC_RELAXED, __HIP_MEMORY_SCOPE_AGENT) < target) {
        __builtin_amdgcn_s_sleep(2);
        if (++g > (1 << 20)) break;   // deadlock bailout -> visible failure, no hang
    }
}

// 4x4 transpose within each lane-quad across regs v0..v3. (verified rounds 1-4)
__device__ __forceinline__ void quadtr(f32x4 a, int lane,
                                       float& z0, float& z1, float& z2, float& z3) {
    float x0 = a[0], x1 = a[1], x2 = a[2], x3 = a[3];
    float s0 = __shfl_xor(x0, 1), s1 = __shfl_xor(x1, 1),
          s2 = __shfl_xor(x2, 1), s3 = __shfl_xor(x3, 1);
    bool o1 = (lane & 1) != 0;
    float y0 = o1 ? s1 : x0;
    float y1 = o1 ? x1 : s0;
    float y2 = o1 ? s3 : x2;
    float y3 = o1 ? x3 : s2;
    float t0 = __shfl_xor(y0, 2), t1 = __shfl_xor(y1, 2),
          t2 = __shfl_xor(y2, 2), t3 = __shfl_xor(y3, 2);
    bool o2 = (lane & 2) != 0;
    z0 = o2 ? t2 : y0;
    z1 = o2 ? t3 : y1;
    z2 = o2 ? y2 : t0;
    z3 = o2 ? y3 : t1;
}

// ---------------- packing kernels (unchanged, verified) ----------------

__global__ void pack_enc_kernel(const float* __restrict__ Wx, const float* __restrict__ Wh,
                                const float* __restrict__ bsrc,
                                __hip_bfloat16* __restrict__ Wp, float* __restrict__ bp)
{
    int n = blockIdx.y;
    int k = blockIdx.x * 256 + threadIdx.x;
    int j = n >> 2, g = n & 3;
    int col = g * NHE + j;
    if (k < KENC) {
        float v = (k < NI) ? Wx[k * NENC + col] : Wh[(k - NI) * NENC + col];
        Wp[(size_t)n * KENC + k] = __float2bfloat16(v);
    }
    if (blockIdx.x == 0 && threadIdx.x == 0) bp[n] = bsrc[col];
}

__global__ void pack_dec_kernel(const float* __restrict__ Wh, const float* __restrict__ ow,
                                const float* __restrict__ bsrc,
                                __hip_bfloat16* __restrict__ Wp, float* __restrict__ bp)
{
    int n = blockIdx.y;          // 0..1151
    int k = threadIdx.x;         // 0..255
    float v;
    if (n < 1024) {
        int j = n >> 2, g = n & 3;
        int col = g * NH + j;
        v = Wh[k * 1024 + col];
        if (k == 0) bp[n] = bsrc[col];
    } else if (n < 1088) {
        v = ow[k * NI + (n - 1024)];
    } else {
        v = 0.0f;
    }
    Wp[(size_t)n * KDEC + k] = __float2bfloat16(v);
}

__global__ void pack_xb_kernel(const float* __restrict__ X, const int* __restrict__ W,
                               const float* __restrict__ A, __hip_bfloat16* __restrict__ Xb)
{
    int idx = blockIdx.x * 256 + threadIdx.x;
    int i = idx & 63;
    int t1 = idx >> 6;
    int b = t1 & 1023;
    int d = t1 >> 10;
    int src = (b * ND + d) * NI + i;
    float v = W[src] ? X[src] : A[d * NI + i];
    Xb[idx] = __float2bfloat16(v);
}

// ---------------- persistent encoder ----------------
// grid (32 m, 16 n), 256 threads (4 waves). Block tile 32 rows x 128 gate-cols.
// Wave tile 32x32 (breg[2][18]). 2 blocks/CU (39.7 KB LDS) from different m-chains
// -> sync latency of one chain hidden by the other chain's compute.
// h exchange through LLC via relaxed device-scope atomics; NO fences (verified r4).
__global__ __launch_bounds__(256, 2) void enc_persist(
    const __hip_bfloat16* __restrict__ Xb,
    __hip_bfloat16* __restrict__ h0buf, __hip_bfloat16* __restrict__ h1buf,
    float* __restrict__ cenc,
    const __hip_bfloat16* __restrict__ Wp, const float* __restrict__ bp,
    const float* __restrict__ pi, const float* __restrict__ pf, const float* __restrict__ po,
    int* __restrict__ wrflag)
{
    __shared__ __align__(16) unsigned short Alds[32][ESTR]; // 37376 B
    __shared__ __align__(16) unsigned short Hlds[32][36];   // 2304 B

    const int tid  = threadIdx.x;
    const int lane = tid & 63;
    const int wv   = tid >> 6;     // 0..3
    const int bm   = blockIdx.x;   // 0..31
    const int bn   = blockIdx.y;   // 0..15
    const int m0   = bm * 32;
    const int lr   = lane & 15;
    const int q    = lane >> 4;    // 0..3
    const int lk   = q * 8;

    // persistent weight fragments: cols bn*128 + wv*32 + ni*16 + lr
    bf16x8 breg[2][18];
    #pragma unroll
    for (int ni = 0; ni < 2; ++ni) {
        const __hip_bfloat16* wb = Wp + (size_t)(bn * 128 + wv * 32 + ni * 16 + lr) * KENC + lk;
        #pragma unroll
        for (int i = 0; i < 18; ++i)
            breg[ni][i] = *reinterpret_cast<const bf16x8*>(wb + i * 32);
    }

    // per-lane epilogue params
    const int u = lr >> 2;
    const int e = lane & 3;
    float4 bb[2];
    float ppi[2], ppf[2], ppo[2];
    int jl[2];
    #pragma unroll
    for (int ni = 0; ni < 2; ++ni) {
        jl[ni] = wv * 8 + ni * 4 + u;
        int jg = bn * 32 + jl[ni];
        bb[ni] = *reinterpret_cast<const float4*>(bp + 4 * jg);
        ppi[ni] = pi[jg]; ppf[ni] = pf[jg]; ppo[ni] = po[jg];
    }
    const int rowb = 4 * q + e;

    float creg[2][2] = {{0.f, 0.f}, {0.f, 0.f}};
    __hip_bfloat16* hbuf[2] = {h0buf, h1buf};

    for (int t = 0; t < ND; ++t) {
        // stage x-part (independent of h_t) before the spin
        {
            int row = tid >> 3, ch = tid & 7;
            *reinterpret_cast<bf16x8*>(&Alds[row][ch * 8]) =
                *reinterpret_cast<const bf16x8*>(Xb + ((size_t)t * NB + m0 + row) * NI + ch * 8);
        }
        if (t > 0 && tid == 0) spin_ge(&wrflag[bm * ND + (t - 1)], 16);
        __syncthreads();

        // stage h via coherent 8B loads (LLC): 32 rows x 128 ULLs = 4096 ULLs
        {
            const unsigned long long* hsrc =
                (const unsigned long long*)(hbuf[t & 1] + (size_t)m0 * NHE);
            #pragma unroll
            for (int it = 0; it < 16; ++it) {
                int idx = tid + it * 256;
                int row = idx >> 7, c8 = idx & 127;
                unsigned long long v = ld_ull(hsrc + (size_t)row * 128 + c8);
                *reinterpret_cast<unsigned long long*>(&Alds[row][64 + c8 * 4]) = v;
            }
        }
        __syncthreads();

        // K-loop: 18 chunks, 2 A-frag reads + 4 MFMAs per chunk
        f32x4 acc[2][2];
        #pragma unroll
        for (int mi = 0; mi < 2; ++mi)
            #pragma unroll
            for (int ni = 0; ni < 2; ++ni) acc[mi][ni] = {0.f, 0.f, 0.f, 0.f};
        #pragma unroll
        for (int i = 0; i < 18; ++i) {
            bf16x8 a[2];
            #pragma unroll
            for (int mi = 0; mi < 2; ++mi)
                a[mi] = *reinterpret_cast<const bf16x8*>(&Alds[16 * mi + lr][i * 32 + lk]);
            #pragma unroll
            for (int mi = 0; mi < 2; ++mi)
                #pragma unroll
                for (int ni = 0; ni < 2; ++ni)
                    acc[mi][ni] = mfma16(a[mi], breg[ni][i], acc[mi][ni]);
        }

        // epilogue: in-register peephole update -> Hlds
        #pragma unroll
        for (int mi = 0; mi < 2; ++mi) {
            #pragma unroll
            for (int ni = 0; ni < 2; ++ni) {
                float z0, z1, z2, z3;
                quadtr(acc[mi][ni], lane, z0, z1, z2, z3);
                float c_old = creg[mi][ni];
                float gi = sigmf(z0 + bb[ni].x + ppi[ni] * c_old);
                float gf = sigmf(z1 + bb[ni].y + ppf[ni] * c_old);
                float cn = gf * c_old + gi * tanh_f(z2 + bb[ni].z);
                float go = sigmf(z3 + bb[ni].w + ppo[ni] * cn);
                creg[mi][ni] = cn;
                int row = 16 * mi + rowb;
                __hip_bfloat16 hv = __float2bfloat16(go * tanh_f(cn));
                Hlds[row][jl[ni]] = reinterpret_cast<unsigned short&>(hv);
                if (t == ND - 1)
                    cenc[(size_t)(m0 + row) * NHE + bn * 32 + jl[ni]] = cn;
            }
        }
        __syncthreads();

        if (t < ND - 1) {
            // coalesced coherent h store: 32 rows x 64 B
            {
                int row = tid >> 3, k8 = tid & 7;
                __hip_bfloat16* hdst = hbuf[(t + 1) & 1];
                unsigned long long v =
                    *reinterpret_cast<const unsigned long long*>(&Hlds[row][k8 * 4]);
                st_ull((unsigned long long*)(hdst + (size_t)(m0 + row) * NHE + bn * 32 + k8 * 4), v);
            }
            __syncthreads();  // stores drained (vmcnt(0) at barrier) before flag
            if (tid == 0)
                __hip_atomic_fetch_add(&wrflag[bm * ND + t], 1,
                                       __ATOMIC_RELAXED, __HIP_MEMORY_SCOPE_AGENT);
        }
    }
}

// ---------------- persistent decoder (+ fused projection) ----------------
// grid (32 m, 9 n): bn 0..7 gate blocks (32x128), bn==8 projection (32x64).
__global__ __launch_bounds__(256, 2) void dec_persist(
    __hip_bfloat16* __restrict__ hd0, __hip_bfloat16* __restrict__ hd1,
    const float* __restrict__ zdec,
    const __hip_bfloat16* __restrict__ Wp, const float* __restrict__ bp,
    const float* __restrict__ pi, const float* __restrict__ pf, const float* __restrict__ po,
    const float* __restrict__ ob,
    float* __restrict__ ox, float* __restrict__ oxr,
    int* __restrict__ wr2, int* __restrict__ prd)
{
    __shared__ __align__(16) unsigned short Alds[32][DSTR]; // 16896 B
    __shared__ __align__(16) unsigned short Hlds[32][36];

    const int tid  = threadIdx.x;
    const int lane = tid & 63;
    const int wv   = tid >> 6;
    const int bm   = blockIdx.x;   // 0..31
    const int bn   = blockIdx.y;   // 0..8
    const int m0   = bm * 32;
    const int lr   = lane & 15;
    const int q    = lane >> 4;
    const int lk   = q * 8;

    __hip_bfloat16* hbuf[2] = {hd0, hd1};

    if (bn < 8) {
        // ---- gate blocks ----
        bf16x8 breg[2][8];
        #pragma unroll
        for (int ni = 0; ni < 2; ++ni) {
            const __hip_bfloat16* wb = Wp + (size_t)(bn * 128 + wv * 32 + ni * 16 + lr) * KDEC + lk;
            #pragma unroll
            for (int i = 0; i < 8; ++i)
                breg[ni][i] = *reinterpret_cast<const bf16x8*>(wb + i * 32);
        }

        const int u = lr >> 2;
        const int e = lane & 3;
        float4 bb[2];
        float ppi[2], ppf[2], ppo[2];
        int jl[2];
        #pragma unroll
        for (int ni = 0; ni < 2; ++ni) {
            jl[ni] = wv * 8 + ni * 4 + u;
            int jg = bn * 32 + jl[ni];
            bb[ni] = *reinterpret_cast<const float4*>(bp + 4 * jg);
            ppi[ni] = pi[jg]; ppf[ni] = pf[jg]; ppo[ni] = po[jg];
        }
        const int rowb = 4 * q + e;

        float creg[2][2];
        #pragma unroll
        for (int mi = 0; mi < 2; ++mi)
            #pragma unroll
            for (int ni = 0; ni < 2; ++ni)
                creg[mi][ni] = zdec[(size_t)(m0 + 16 * mi + rowb) * NH + bn * 32 + jl[ni]];

        for (int t = 0; t < ND; ++t) {
            if (tid == 0) {
                if (t >= 1) spin_ge(&wr2[bm * ND + (t - 1)], 8);
                if (t >= 2) spin_ge(&prd[bm * ND + (t - 2)], 1);
            }
            __syncthreads();

            // stage h: 32 rows x 64 ULLs = 2048 ULLs (FIXED: was 1024 = half tile in r5)
            {
                const unsigned long long* hsrc =
                    (const unsigned long long*)(hbuf[t & 1] + (size_t)m0 * NH);
                #pragma unroll
                for (int it = 0; it < 8; ++it) {
                    int idx = tid + it * 256;
                    int row = idx >> 6, c8 = idx & 63;
                    unsigned long long v = ld_ull(hsrc + (size_t)row * 64 + c8);
                    *reinterpret_cast<unsigned long long*>(&Alds[row][c8 * 4]) = v;
                }
            }
            __syncthreads();

            f32x4 acc[2][2];
            #pragma unroll
            for (int mi = 0; mi < 2; ++mi)
                #pragma unroll
                for (int ni = 0; ni < 2; ++ni) acc[mi][ni] = {0.f, 0.f, 0.f, 0.f};
            #pragma unroll
            for (int i = 0; i < 8; ++i) {
                bf16x8 a[2];
                #pragma unroll
                for (int mi = 0; mi < 2; ++mi)
                    a[mi] = *reinterpret_cast<const bf16x8*>(&Alds[16 * mi + lr][i * 32 + lk]);
                #pragma unroll
                for (int mi = 0; mi < 2; ++mi)
                    #pragma unroll
                    for (int ni = 0; ni < 2; ++ni)
                        acc[mi][ni] = mfma16(a[mi], breg[ni][i], acc[mi][ni]);
            }

            #pragma unroll
            for (int mi = 0; mi < 2; ++mi) {
                #pragma unroll
                for (int ni = 0; ni < 2; ++ni) {
                    float z0, z1, z2, z3;
                    quadtr(acc[mi][ni], lane, z0, z1, z2, z3);
                    float c_old = creg[mi][ni];
                    float gi = sigmf(z0 + bb[ni].x + ppi[ni] * c_old);
                    float gf = sigmf(z1 + bb[ni].y + ppf[ni] * c_old);
                    float cn = gf * c_old + gi * tanh_f(z2 + bb[ni].z);
                    float go = sigmf(z3 + bb[ni].w + ppo[ni] * cn);
                    creg[mi][ni] = cn;
                    int row = 16 * mi + rowb;
                    __hip_bfloat16 hv = __float2bfloat16(go * tanh_f(cn));
                    Hlds[row][jl[ni]] = reinterpret_cast<unsigned short&>(hv);
                }
            }
            __syncthreads();

            {
                int row = tid >> 3, k8 = tid & 7;
                __hip_bfloat16* hdst = hbuf[(t + 1) & 1];
                unsigned long long v =
                    *reinterpret_cast<const unsigned long long*>(&Hlds[row][k8 * 4]);
                st_ull((unsigned long long*)(hdst + (size_t)(m0 + row) * NH + bn * 32 + k8 * 4), v);
            }
            __syncthreads();
            if (tid == 0)
                __hip_atomic_fetch_add(&wr2[bm * ND + t], 1,
                                       __ATOMIC_RELAXED, __HIP_MEMORY_SCOPE_AGENT);
        }
    } else {
        // ---- projection block: x_raw[:, s, :] = h_{s+1} @ ow + ob ----
        bf16x8 breg[8];
        const __hip_bfloat16* wb = Wp + (size_t)(1024 + wv * 16 + lr) * KDEC + lk;
        #pragma unroll
        for (int i = 0; i < 8; ++i)
            breg[i] = *reinterpret_cast<const bf16x8*>(wb + i * 32);
        const float obv = ob[wv * 16 + lr];

        for (int s = 0; s < ND; ++s) {
            if (tid == 0) spin_ge(&wr2[bm * ND + s], 8);
            __syncthreads();

            // stage h: 32 rows x 64 ULLs = 2048 ULLs (FIXED: was 1024 = half tile in r5)
            {
                const unsigned long long* hsrc =
                    (const unsigned long long*)(hbuf[(s + 1) & 1] + (size_t)m0 * NH);
                #pragma unroll
                for (int it = 0; it < 8; ++it) {
                    int idx = tid + it * 256;
                    int row = idx >> 6, c8 = idx & 63;
                    unsigned long long v = ld_ull(hsrc + (size_t)row * 64 + c8);
                    *reinterpret_cast<unsigned long long*>(&Alds[row][c8 * 4]) = v;
                }
            }
            __syncthreads();
            // h copied to LDS -> gates may overwrite the buffer (loads drained at barrier)
            if (tid == 0)
                __hip_atomic_fetch_add(&prd[bm * ND + s], 1,
                                       __ATOMIC_RELAXED, __HIP_MEMORY_SCOPE_AGENT);

            f32x4 acc[2];
            #pragma unroll
            for (int mi = 0; mi < 2; ++mi) acc[mi] = {0.f, 0.f, 0.f, 0.f};
            #pragma unroll
            for (int i = 0; i < 8; ++i) {
                bf16x8 a[2];
                #pragma unroll
                for (int mi = 0; mi < 2; ++mi)
                    a[mi] = *reinterpret_cast<const bf16x8*>(&Alds[16 * mi + lr][i * 32 + lk]);
                #pragma unroll
                for (int mi = 0; mi < 2; ++mi)
                    acc[mi] = mfma16(a[mi], breg[i], acc[mi]);
            }

            int colp = wv * 16 + lr;
            #pragma unroll
            for (int mi = 0; mi < 2; ++mi) {
                #pragma unroll
                for (int v = 0; v < 4; ++v) {
                    int row = m0 + 16 * mi + 4 * q + v;
                    float val = acc[mi][v] + obv;
                    size_t off = (size_t)row * (ND * NI) + (size_t)s * NI + colp;
                    oxr[off] = val;
                    ox[off]  = sigmf(val);
                }
            }
        }
    }
}

// ---------------- middle: z = mu + exp(0.5*ls)*noise ----------------
__global__ void mid_kernel(const float* __restrict__ cenc, const float* __restrict__ noise,
                           float* __restrict__ zdec, float* __restrict__ oz,
                           float* __restrict__ omut, float* __restrict__ olst)
{
    int idx = blockIdx.x * 256 + threadIdx.x;  // < 262144
    int b = idx >> 8, h = idx & 255;
    float mu = cenc[b * NHE + h];
    float ls = cenc[b * NHE + NH + h];
    float zz = mu + expf(0.5f * ls) * noise[idx];
    omut[idx] = mu;
    olst[idx] = ls;
    oz[idx]   = zz;
    zdec[idx] = zz;
}

// ---------------- mixture params ----------------
__global__ void mix_kernel(const float* __restrict__ mu_in, const float* __restrict__ s2_in,
                           const float* __restrict__ phi_in,
                           float* __restrict__ mu_out, float* __restrict__ s2_out,
                           float* __restrict__ phi_out)
{
    int idx = blockIdx.x * 256 + threadIdx.x;  // < 2048
    mu_out[idx] = mu_in[idx];
    float x = s2_in[idx];
    s2_out[idx] = (x > 20.0f) ? x : log1pf(expf(x));
    if (idx == 0) {
        float m = phi_in[0];
        for (int k = 1; k < 8; ++k) m = fmaxf(m, phi_in[k]);
        float e[8], s = 0.0f;
        for (int k = 0; k < 8; ++k) { e[k] = expf(phi_in[k] - m); s += e[k]; }
        for (int k = 0; k < 8; ++k) phi_out[k] = e[k] / s;
    }
}

// ---------------- host ----------------
extern "C" void kernel_launch(void* const* d_in, const int* in_sizes, int n_in,
                              void* d_out, int out_size, void* d_ws, size_t ws_size,
                              hipStream_t stream)
{
    const float* X     = (const float*)d_in[0];
    const int*   W     = (const int*)d_in[1];
    const float* noise = (const float*)d_in[2];
    const float* A     = (const float*)d_in[3];
    const float* eWx   = (const float*)d_in[4];
    const float* eWh   = (const float*)d_in[5];
    const float* eb    = (const float*)d_in[6];
    const float* epi   = (const float*)d_in[7];
    const float* epf   = (const float*)d_in[8];
    const float* epo   = (const float*)d_in[9];
    const float* dWh   = (const float*)d_in[11];
    const float* db    = (const float*)d_in[12];
    const float* dpi   = (const float*)d_in[13];
    const float* dpf   = (const float*)d_in[14];
    const float* dpo   = (const float*)d_in[15];
    const float* ow    = (const float*)d_in[16];
    const float* ob    = (const float*)d_in[17];
    const float* muc   = (const float*)d_in[18];
    const float* s2c   = (const float*)d_in[19];
    const float* phic  = (const float*)d_in[20];

    float* out = (float*)d_out;
    float* o_x    = out;
    float* o_xraw = out + 8388608;
    float* o_muc  = out + 16777216;
    float* o_s2c  = out + 16779264;
    float* o_phic = out + 16781312;
    float* o_z    = out + 16781320;
    float* o_mut  = out + 17043464;
    float* o_lst  = out + 17305608;

    char* ws = (char*)d_ws;
    __hip_bfloat16* Wencp = (__hip_bfloat16*)(ws + 0);          // 2359296
    __hip_bfloat16* Wdecp = (__hip_bfloat16*)(ws + 2359296);    // 589824
    float*          bencp = (float*)(ws + 2949120);             // 8192
    float*          bdecp = (float*)(ws + 2957312);             // 8192
    __hip_bfloat16* Xb    = (__hip_bfloat16*)(ws + 2965504);    // 16777216
    __hip_bfloat16* he0   = (__hip_bfloat16*)(ws + 19742720);   // 1048576
    __hip_bfloat16* he1   = (__hip_bfloat16*)(ws + 20791296);   // 1048576
    float*          cenc  = (float*)(ws + 21839872);            // 2097152
    __hip_bfloat16* hd0   = (__hip_bfloat16*)(ws + 23937024);   // 524288
    __hip_bfloat16* hd1   = (__hip_bfloat16*)(ws + 24461312);   // 524288
    float*          zdec  = (float*)(ws + 24985600);            // 1048576
    int*            encwr = (int*)(ws + 26034176);              // 16384
    int*            decwr = (int*)(ws + 26050560);              // 16384
    int*            decpr = (int*)(ws + 26066944);              // 16384 (end 26083328)

    hipMemsetAsync(he0, 0, 1048576, stream);
    hipMemsetAsync(hd0, 0, 524288, stream);
    hipMemsetAsync(encwr, 0, 49152, stream);  // encwr+decwr+decpr contiguous

    pack_enc_kernel<<<dim3(3, 2048), 256, 0, stream>>>(eWx, eWh, eb, Wencp, bencp);
    pack_dec_kernel<<<dim3(1, 1152), 256, 0, stream>>>(dWh, ow, db, Wdecp, bdecp);
    pack_xb_kernel<<<32768, 256, 0, stream>>>(X, W, A, Xb);

    enc_persist<<<dim3(32, 16), 256, 0, stream>>>(
        Xb, he0, he1, cenc, Wencp, bencp, epi, epf, epo, encwr);

    mid_kernel<<<1024, 256, 0, stream>>>(cenc, noise, zdec, o_z, o_mut, o_lst);
    mix_kernel<<<8, 256, 0, stream>>>(muc, s2c, phic, o_muc, o_s2c, o_phic);

    dec_persist<<<dim3(32, 9), 256, 0, stream>>>(
        hd0, hd1, zdec, Wdecp, bdecp, dpi, dpf, dpo, ob, o_x, o_xraw, decwr, decpr);
}

// Round 7
// 1703.294 us; speedup vs baseline: 1.9127x; 1.0147x over previous
//
#include <hip/hip_runtime.h>
#include <hip/hip_bf16.h>

typedef __attribute__((ext_vector_type(4))) float f32x4;
typedef __attribute__((ext_vector_type(8))) short bf16x8;

#define NB 1024   // batch
#define ND 128    // time steps
#define NI 64     // input dim
#define NH 256    // dec hidden
#define NHE 512   // enc hidden
#define KENC 576  // NI + NHE
#define NENC 2048 // 4*NHE
#define KDEC 256
#define ESTR 584  // enc A-tile stride (elems): 8*73, 16B-aligned rows
#define DSTR 264  // dec A-tile stride: 8*33

__device__ __forceinline__ float sigmf(float x) { return 1.0f / (1.0f + __expf(-x)); }
__device__ __forceinline__ float tanh_f(float x) { return 1.0f - 2.0f / (__expf(2.0f * x) + 1.0f); }

__device__ __forceinline__ f32x4 mfma16(bf16x8 a, bf16x8 b, f32x4 c) {
    return __builtin_amdgcn_mfma_f32_16x16x32_bf16(a, b, c, 0, 0, 0);
}

// device-scope coherent (LLC write-through / LLC read) accesses — verified r4/r6
__device__ __forceinline__ void st_ull(unsigned long long* p, unsigned long long v) {
    __hip_atomic_store(p, v, __ATOMIC_RELAXED, __HIP_MEMORY_SCOPE_AGENT);
}
__device__ __forceinline__ unsigned long long ld_ull(const unsigned long long* p) {
    return __hip_atomic_load(p, __ATOMIC_RELAXED, __HIP_MEMORY_SCOPE_AGENT);
}
__device__ __forceinline__ void st_flag(int* p) {
    __hip_atomic_store(p, 1, __ATOMIC_RELAXED, __HIP_MEMORY_SCOPE_AGENT);
}

// wave-parallel spin: lanes [0,n) poll flags[lane]; lane==n polls *extra if non-null.
// Every wave calls this independently — no barrier, no single-thread bottleneck.
__device__ __forceinline__ void wspin(const int* flags, int n, int lane, const int* extra) {
    int g = 0;
    for (;;) {
        int v = 1;
        if (lane < n)
            v = __hip_atomic_load(flags + lane, __ATOMIC_RELAXED, __HIP_MEMORY_SCOPE_AGENT);
        else if (extra != nullptr && lane == n)
            v = __hip_atomic_load(extra, __ATOMIC_RELAXED, __HIP_MEMORY_SCOPE_AGENT);
        if (__all(v != 0)) return;
        __builtin_amdgcn_s_sleep(1);
        if (++g > (1 << 20)) return;  // deadlock bailout -> visible failure, no hang
    }
}

// 4x4 transpose within each lane-quad across regs v0..v3. (verified rounds 1-6)
__device__ __forceinline__ void quadtr(f32x4 a, int lane,
                                       float& z0, float& z1, float& z2, float& z3) {
    float x0 = a[0], x1 = a[1], x2 = a[2], x3 = a[3];
    float s0 = __shfl_xor(x0, 1), s1 = __shfl_xor(x1, 1),
          s2 = __shfl_xor(x2, 1), s3 = __shfl_xor(x3, 1);
    bool o1 = (lane & 1) != 0;
    float y0 = o1 ? s1 : x0;
    float y1 = o1 ? x1 : s0;
    float y2 = o1 ? s3 : x2;
    float y3 = o1 ? x3 : s2;
    float t0 = __shfl_xor(y0, 2), t1 = __shfl_xor(y1, 2),
          t2 = __shfl_xor(y2, 2), t3 = __shfl_xor(y3, 2);
    bool o2 = (lane & 2) != 0;
    z0 = o2 ? t2 : y0;
    z1 = o2 ? t3 : y1;
    z2 = o2 ? y2 : t0;
    z3 = o2 ? y3 : t1;
}

// ---------------- packing kernels (unchanged, verified) ----------------

__global__ void pack_enc_kernel(const float* __restrict__ Wx, const float* __restrict__ Wh,
                                const float* __restrict__ bsrc,
                                __hip_bfloat16* __restrict__ Wp, float* __restrict__ bp)
{
    int n = blockIdx.y;
    int k = blockIdx.x * 256 + threadIdx.x;
    int j = n >> 2, g = n & 3;
    int col = g * NHE + j;
    if (k < KENC) {
        float v = (k < NI) ? Wx[k * NENC + col] : Wh[(k - NI) * NENC + col];
        Wp[(size_t)n * KENC + k] = __float2bfloat16(v);
    }
    if (blockIdx.x == 0 && threadIdx.x == 0) bp[n] = bsrc[col];
}

__global__ void pack_dec_kernel(const float* __restrict__ Wh, const float* __restrict__ ow,
                                const float* __restrict__ bsrc,
                                __hip_bfloat16* __restrict__ Wp, float* __restrict__ bp)
{
    int n = blockIdx.y;          // 0..1151
    int k = threadIdx.x;         // 0..255
    float v;
    if (n < 1024) {
        int j = n >> 2, g = n & 3;
        int col = g * NH + j;
        v = Wh[k * 1024 + col];
        if (k == 0) bp[n] = bsrc[col];
    } else if (n < 1088) {
        v = ow[k * NI + (n - 1024)];
    } else {
        v = 0.0f;
    }
    Wp[(size_t)n * KDEC + k] = __float2bfloat16(v);
}

__global__ void pack_xb_kernel(const float* __restrict__ X, const int* __restrict__ W,
                               const float* __restrict__ A, __hip_bfloat16* __restrict__ Xb)
{
    int idx = blockIdx.x * 256 + threadIdx.x;
    int i = idx & 63;
    int t1 = idx >> 6;
    int b = t1 & 1023;
    int d = t1 >> 10;
    int src = (b * ND + d) * NI + i;
    float v = W[src] ? X[src] : A[d * NI + i];
    Xb[idx] = __float2bfloat16(v);
}

// ---------------- persistent encoder ----------------
// grid (32 m, 16 n), 256 threads (4 waves). Block tile 32 rows x 128 gate-cols.
// Per-producer flags (atomic store, no RMW); wave-parallel barrier-free spin;
// X-part MFMAs overlap producer tails. h exchange via LLC relaxed atomics.
__global__ __launch_bounds__(256, 2) void enc_persist(
    const __hip_bfloat16* __restrict__ Xb,
    __hip_bfloat16* __restrict__ h0buf, __hip_bfloat16* __restrict__ h1buf,
    float* __restrict__ cenc,
    const __hip_bfloat16* __restrict__ Wp, const float* __restrict__ bp,
    const float* __restrict__ pi, const float* __restrict__ pf, const float* __restrict__ po,
    int* __restrict__ encfl)
{
    __shared__ __align__(16) unsigned short Alds[32][ESTR]; // 37376 B
    __shared__ __align__(16) unsigned short Hlds[32][36];   // 2304 B

    const int tid  = threadIdx.x;
    const int lane = tid & 63;
    const int wv   = tid >> 6;     // 0..3
    const int bm   = blockIdx.x;   // 0..31
    const int bn   = blockIdx.y;   // 0..15
    const int m0   = bm * 32;
    const int lr   = lane & 15;
    const int q    = lane >> 4;    // 0..3
    const int lk   = q * 8;

    // persistent weight fragments: cols bn*128 + wv*32 + ni*16 + lr
    bf16x8 breg[2][18];
    #pragma unroll
    for (int ni = 0; ni < 2; ++ni) {
        const __hip_bfloat16* wb = Wp + (size_t)(bn * 128 + wv * 32 + ni * 16 + lr) * KENC + lk;
        #pragma unroll
        for (int i = 0; i < 18; ++i)
            breg[ni][i] = *reinterpret_cast<const bf16x8*>(wb + i * 32);
    }

    // per-lane epilogue params
    const int u = lr >> 2;
    const int e = lane & 3;
    float4 bb[2];
    float ppi[2], ppf[2], ppo[2];
    int jl[2];
    #pragma unroll
    for (int ni = 0; ni < 2; ++ni) {
        jl[ni] = wv * 8 + ni * 4 + u;
        int jg = bn * 32 + jl[ni];
        bb[ni] = *reinterpret_cast<const float4*>(bp + 4 * jg);
        ppi[ni] = pi[jg]; ppf[ni] = pf[jg]; ppo[ni] = po[jg];
    }
    const int rowb = 4 * q + e;

    float creg[2][2] = {{0.f, 0.f}, {0.f, 0.f}};
    __hip_bfloat16* hbuf[2] = {h0buf, h1buf};

    for (int t = 0; t < ND; ++t) {
        // [A] stage x (independent of h_t); prior-step reads finished at prev barrier
        {
            int row = tid >> 3, ch = tid & 7;
            *reinterpret_cast<bf16x8*>(&Alds[row][ch * 8]) =
                *reinterpret_cast<const bf16x8*>(Xb + ((size_t)t * NB + m0 + row) * NI + ch * 8);
        }
        __syncthreads();

        // [B] X-part MFMAs (K chunks 0,1) — no h dependency, overlaps producers
        f32x4 acc[2][2];
        #pragma unroll
        for (int mi = 0; mi < 2; ++mi)
            #pragma unroll
            for (int ni = 0; ni < 2; ++ni) acc[mi][ni] = {0.f, 0.f, 0.f, 0.f};
        #pragma unroll
        for (int i = 0; i < 2; ++i) {
            bf16x8 a[2];
            #pragma unroll
            for (int mi = 0; mi < 2; ++mi)
                a[mi] = *reinterpret_cast<const bf16x8*>(&Alds[16 * mi + lr][i * 32 + lk]);
            #pragma unroll
            for (int mi = 0; mi < 2; ++mi)
                #pragma unroll
                for (int ni = 0; ni < 2; ++ni)
                    acc[mi][ni] = mfma16(a[mi], breg[ni][i], acc[mi][ni]);
        }

        // [C] wave-parallel spin on 16 per-producer flags (no barrier, no RMW)
        if (t > 0) wspin(encfl + (size_t)(bm * ND + (t - 1)) * 16, 16, lane, nullptr);

        // [D] stage h via coherent 8B loads: 32 rows x 128 ULLs
        {
            const unsigned long long* hsrc =
                (const unsigned long long*)(hbuf[t & 1] + (size_t)m0 * NHE);
            #pragma unroll
            for (int it = 0; it < 16; ++it) {
                int idx = tid + it * 256;
                int row = idx >> 7, c8 = idx & 127;
                unsigned long long v = ld_ull(hsrc + (size_t)row * 128 + c8);
                *reinterpret_cast<unsigned long long*>(&Alds[row][64 + c8 * 4]) = v;
            }
        }
        __syncthreads();

        // [F] h-part MFMAs (K chunks 2..17)
        #pragma unroll
        for (int i = 2; i < 18; ++i) {
            bf16x8 a[2];
            #pragma unroll
            for (int mi = 0; mi < 2; ++mi)
                a[mi] = *reinterpret_cast<const bf16x8*>(&Alds[16 * mi + lr][i * 32 + lk]);
            #pragma unroll
            for (int mi = 0; mi < 2; ++mi)
                #pragma unroll
                for (int ni = 0; ni < 2; ++ni)
                    acc[mi][ni] = mfma16(a[mi], breg[ni][i], acc[mi][ni]);
        }

        // [G] epilogue: in-register peephole update -> Hlds
        #pragma unroll
        for (int mi = 0; mi < 2; ++mi) {
            #pragma unroll
            for (int ni = 0; ni < 2; ++ni) {
                float z0, z1, z2, z3;
                quadtr(acc[mi][ni], lane, z0, z1, z2, z3);
                float c_old = creg[mi][ni];
                float gi = sigmf(z0 + bb[ni].x + ppi[ni] * c_old);
                float gf = sigmf(z1 + bb[ni].y + ppf[ni] * c_old);
                float cn = gf * c_old + gi * tanh_f(z2 + bb[ni].z);
                float go = sigmf(z3 + bb[ni].w + ppo[ni] * cn);
                creg[mi][ni] = cn;
                int row = 16 * mi + rowb;
                __hip_bfloat16 hv = __float2bfloat16(go * tanh_f(cn));
                Hlds[row][jl[ni]] = reinterpret_cast<unsigned short&>(hv);
                if (t == ND - 1)
                    cenc[(size_t)(m0 + row) * NHE + bn * 32 + jl[ni]] = cn;
            }
        }
        __syncthreads();

        if (t < ND - 1) {
            // [I] coalesced coherent h store: 32 rows x 64 B
            {
                int row = tid >> 3, k8 = tid & 7;
                __hip_bfloat16* hdst = hbuf[(t + 1) & 1];
                unsigned long long v =
                    *reinterpret_cast<const unsigned long long*>(&Hlds[row][k8 * 4]);
                st_ull((unsigned long long*)(hdst + (size_t)(m0 + row) * NHE + bn * 32 + k8 * 4), v);
            }
            __syncthreads();  // all waves' stores drained (vmcnt(0) at barrier)
            // [J] per-producer presence flag (atomic store, no RMW)
            if (tid == 0) st_flag(encfl + (size_t)(bm * ND + t) * 16 + bn);
        }
    }
}

// ---------------- persistent decoder (+ fused projection) ----------------
// grid (32 m, 9 n): bn 0..7 gate blocks (32x128), bn==8 projection (32x64).
__global__ __launch_bounds__(256, 2) void dec_persist(
    __hip_bfloat16* __restrict__ hd0, __hip_bfloat16* __restrict__ hd1,
    const float* __restrict__ zdec,
    const __hip_bfloat16* __restrict__ Wp, const float* __restrict__ bp,
    const float* __restrict__ pi, const float* __restrict__ pf, const float* __restrict__ po,
    const float* __restrict__ ob,
    float* __restrict__ ox, float* __restrict__ oxr,
    int* __restrict__ decfl, int* __restrict__ decpr)
{
    __shared__ __align__(16) unsigned short Alds[32][DSTR]; // 16896 B
    __shared__ __align__(16) unsigned short Hlds[32][36];

    const int tid  = threadIdx.x;
    const int lane = tid & 63;
    const int wv   = tid >> 6;
    const int bm   = blockIdx.x;   // 0..31
    const int bn   = blockIdx.y;   // 0..8
    const int m0   = bm * 32;
    const int lr   = lane & 15;
    const int q    = lane >> 4;
    const int lk   = q * 8;

    __hip_bfloat16* hbuf[2] = {hd0, hd1};

    if (bn < 8) {
        // ---- gate blocks ----
        bf16x8 breg[2][8];
        #pragma unroll
        for (int ni = 0; ni < 2; ++ni) {
            const __hip_bfloat16* wb = Wp + (size_t)(bn * 128 + wv * 32 + ni * 16 + lr) * KDEC + lk;
            #pragma unroll
            for (int i = 0; i < 8; ++i)
                breg[ni][i] = *reinterpret_cast<const bf16x8*>(wb + i * 32);
        }

        const int u = lr >> 2;
        const int e = lane & 3;
        float4 bb[2];
        float ppi[2], ppf[2], ppo[2];
        int jl[2];
        #pragma unroll
        for (int ni = 0; ni < 2; ++ni) {
            jl[ni] = wv * 8 + ni * 4 + u;
            int jg = bn * 32 + jl[ni];
            bb[ni] = *reinterpret_cast<const float4*>(bp + 4 * jg);
            ppi[ni] = pi[jg]; ppf[ni] = pf[jg]; ppo[ni] = po[jg];
        }
        const int rowb = 4 * q + e;

        float creg[2][2];
        #pragma unroll
        for (int mi = 0; mi < 2; ++mi)
            #pragma unroll
            for (int ni = 0; ni < 2; ++ni)
                creg[mi][ni] = zdec[(size_t)(m0 + 16 * mi + rowb) * NH + bn * 32 + jl[ni]];

        for (int t = 0; t < ND; ++t) {
            // wave-parallel spin: lanes 0..7 on gate flags of t-1, lane 8 on proj-read of t-2
            if (t >= 1) {
                const int* ex = (t >= 2) ? (decpr + bm * ND + (t - 2)) : nullptr;
                wspin(decfl + (size_t)(bm * ND + (t - 1)) * 8, 8, lane, ex);
            }

            // stage h: 32 rows x 64 ULLs = 2048
            {
                const unsigned long long* hsrc =
                    (const unsigned long long*)(hbuf[t & 1] + (size_t)m0 * NH);
                #pragma unroll
                for (int it = 0; it < 8; ++it) {
                    int idx = tid + it * 256;
                    int row = idx >> 6, c8 = idx & 63;
                    unsigned long long v = ld_ull(hsrc + (size_t)row * 64 + c8);
                    *reinterpret_cast<unsigned long long*>(&Alds[row][c8 * 4]) = v;
                }
            }
            __syncthreads();

            f32x4 acc[2][2];
            #pragma unroll
            for (int mi = 0; mi < 2; ++mi)
                #pragma unroll
                for (int ni = 0; ni < 2; ++ni) acc[mi][ni] = {0.f, 0.f, 0.f, 0.f};
            #pragma unroll
            for (int i = 0; i < 8; ++i) {
                bf16x8 a[2];
                #pragma unroll
                for (int mi = 0; mi < 2; ++mi)
                    a[mi] = *reinterpret_cast<const bf16x8*>(&Alds[16 * mi + lr][i * 32 + lk]);
                #pragma unroll
                for (int mi = 0; mi < 2; ++mi)
                    #pragma unroll
                    for (int ni = 0; ni < 2; ++ni)
                        acc[mi][ni] = mfma16(a[mi], breg[ni][i], acc[mi][ni]);
            }

            #pragma unroll
            for (int mi = 0; mi < 2; ++mi) {
                #pragma unroll
                for (int ni = 0; ni < 2; ++ni) {
                    float z0, z1, z2, z3;
                    quadtr(acc[mi][ni], lane, z0, z1, z2, z3);
                    float c_old = creg[mi][ni];
                    float gi = sigmf(z0 + bb[ni].x + ppi[ni] * c_old);
                    float gf = sigmf(z1 + bb[ni].y + ppf[ni] * c_old);
                    float cn = gf * c_old + gi * tanh_f(z2 + bb[ni].z);
                    float go = sigmf(z3 + bb[ni].w + ppo[ni] * cn);
                    creg[mi][ni] = cn;
                    int row = 16 * mi + rowb;
                    __hip_bfloat16 hv = __float2bfloat16(go * tanh_f(cn));
                    Hlds[row][jl[ni]] = reinterpret_cast<unsigned short&>(hv);
                }
            }
            __syncthreads();

            {
                int row = tid >> 3, k8 = tid & 7;
                __hip_bfloat16* hdst = hbuf[(t + 1) & 1];
                unsigned long long v =
                    *reinterpret_cast<const unsigned long long*>(&Hlds[row][k8 * 4]);
                st_ull((unsigned long long*)(hdst + (size_t)(m0 + row) * NH + bn * 32 + k8 * 4), v);
            }
            __syncthreads();
            if (tid == 0) st_flag(decfl + (size_t)(bm * ND + t) * 8 + bn);
        }
    } else {
        // ---- projection block: x_raw[:, s, :] = h_{s+1} @ ow + ob ----
        bf16x8 breg[8];
        const __hip_bfloat16* wb = Wp + (size_t)(1024 + wv * 16 + lr) * KDEC + lk;
        #pragma unroll
        for (int i = 0; i < 8; ++i)
            breg[i] = *reinterpret_cast<const bf16x8*>(wb + i * 32);
        const float obv = ob[wv * 16 + lr];

        for (int s = 0; s < ND; ++s) {
            wspin(decfl + (size_t)(bm * ND + s) * 8, 8, lane, nullptr);
            __syncthreads();  // prev-iter MFMA ds_reads done before overwriting Alds

            // stage h: 32 rows x 64 ULLs = 2048
            {
                const unsigned long long* hsrc =
                    (const unsigned long long*)(hbuf[(s + 1) & 1] + (size_t)m0 * NH);
                #pragma unroll
                for (int it = 0; it < 8; ++it) {
                    int idx = tid + it * 256;
                    int row = idx >> 6, c8 = idx & 63;
                    unsigned long long v = ld_ull(hsrc + (size_t)row * 64 + c8);
                    *reinterpret_cast<unsigned long long*>(&Alds[row][c8 * 4]) = v;
                }
            }
            __syncthreads();
            // h copied to LDS -> gates may overwrite the buffer
            if (tid == 0) st_flag(decpr + bm * ND + s);

            f32x4 acc[2];
            #pragma unroll
            for (int mi = 0; mi < 2; ++mi) acc[mi] = {0.f, 0.f, 0.f, 0.f};
            #pragma unroll
            for (int i = 0; i < 8; ++i) {
                bf16x8 a[2];
                #pragma unroll
                for (int mi = 0; mi < 2; ++mi)
                    a[mi] = *reinterpret_cast<const bf16x8*>(&Alds[16 * mi + lr][i * 32 + lk]);
                #pragma unroll
                for (int mi = 0; mi < 2; ++mi)
                    acc[mi] = mfma16(a[mi], breg[i], acc[mi]);
            }

            int colp = wv * 16 + lr;
            #pragma unroll
            for (int mi = 0; mi < 2; ++mi) {
                #pragma unroll
                for (int v = 0; v < 4; ++v) {
                    int row = m0 + 16 * mi + 4 * q + v;
                    float val = acc[mi][v] + obv;
                    size_t off = (size_t)row * (ND * NI) + (size_t)s * NI + colp;
                    oxr[off] = val;
                    ox[off]  = sigmf(val);
                }
            }
        }
    }
}

// ---------------- middle: z = mu + exp(0.5*ls)*noise ----------------
__global__ void mid_kernel(const float* __restrict__ cenc, const float* __restrict__ noise,
                           float* __restrict__ zdec, float* __restrict__ oz,
                           float* __restrict__ omut, float* __restrict__ olst)
{
    int idx = blockIdx.x * 256 + threadIdx.x;  // < 262144
    int b = idx >> 8, h = idx & 255;
    float mu = cenc[b * NHE + h];
    float ls = cenc[b * NHE + NH + h];
    float zz = mu + expf(0.5f * ls) * noise[idx];
    omut[idx] = mu;
    olst[idx] = ls;
    oz[idx]   = zz;
    zdec[idx] = zz;
}

// ---------------- mixture params ----------------
__global__ void mix_kernel(const float* __restrict__ mu_in, const float* __restrict__ s2_in,
                           const float* __restrict__ phi_in,
                           float* __restrict__ mu_out, float* __restrict__ s2_out,
                           float* __restrict__ phi_out)
{
    int idx = blockIdx.x * 256 + threadIdx.x;  // < 2048
    mu_out[idx] = mu_in[idx];
    float x = s2_in[idx];
    s2_out[idx] = (x > 20.0f) ? x : log1pf(expf(x));
    if (idx == 0) {
        float m = phi_in[0];
        for (int k = 1; k < 8; ++k) m = fmaxf(m, phi_in[k]);
        float e[8], s = 0.0f;
        for (int k = 0; k < 8; ++k) { e[k] = expf(phi_in[k] - m); s += e[k]; }
        for (int k = 0; k < 8; ++k) phi_out[k] = e[k] / s;
    }
}

// ---------------- host ----------------
extern "C" void kernel_launch(void* const* d_in, const int* in_sizes, int n_in,
                              void* d_out, int out_size, void* d_ws, size_t ws_size,
                              hipStream_t stream)
{
    const float* X     = (const float*)d_in[0];
    const int*   W     = (const int*)d_in[1];
    const float* noise = (const float*)d_in[2];
    const float* A     = (const float*)d_in[3];
    const float* eWx   = (const float*)d_in[4];
    const float* eWh   = (const float*)d_in[5];
    const float* eb    = (const float*)d_in[6];
    const float* epi   = (const float*)d_in[7];
    const float* epf   = (const float*)d_in[8];
    const float* epo   = (const float*)d_in[9];
    const float* dWh   = (const float*)d_in[11];
    const float* db    = (const float*)d_in[12];
    const float* dpi   = (const float*)d_in[13];
    const float* dpf   = (const float*)d_in[14];
    const float* dpo   = (const float*)d_in[15];
    const float* ow    = (const float*)d_in[16];
    const float* ob    = (const float*)d_in[17];
    const float* muc   = (const float*)d_in[18];
    const float* s2c   = (const float*)d_in[19];
    const float* phic  = (const float*)d_in[20];

    float* out = (float*)d_out;
    float* o_x    = out;
    float* o_xraw = out + 8388608;
    float* o_muc  = out + 16777216;
    float* o_s2c  = out + 16779264;
    float* o_phic = out + 16781312;
    float* o_z    = out + 16781320;
    float* o_mut  = out + 17043464;
    float* o_lst  = out + 17305608;

    char* ws = (char*)d_ws;
    __hip_bfloat16* Wencp = (__hip_bfloat16*)(ws + 0);          // 2359296
    __hip_bfloat16* Wdecp = (__hip_bfloat16*)(ws + 2359296);    // 589824
    float*          bencp = (float*)(ws + 2949120);             // 8192
    float*          bdecp = (float*)(ws + 2957312);             // 8192
    __hip_bfloat16* Xb    = (__hip_bfloat16*)(ws + 2965504);    // 16777216
    __hip_bfloat16* he0   = (__hip_bfloat16*)(ws + 19742720);   // 1048576
    __hip_bfloat16* he1   = (__hip_bfloat16*)(ws + 20791296);   // 1048576
    float*          cenc  = (float*)(ws + 21839872);            // 2097152
    __hip_bfloat16* hd0   = (__hip_bfloat16*)(ws + 23937024);   // 524288
    __hip_bfloat16* hd1   = (__hip_bfloat16*)(ws + 24461312);   // 524288
    float*          zdec  = (float*)(ws + 24985600);            // 1048576
    int*            encfl = (int*)(ws + 26034176);              // 32*128*16*4 = 262144
    int*            decfl = (int*)(ws + 26296320);              // 32*128*8*4  = 131072
    int*            decpr = (int*)(ws + 26427392);              // 32*128*4    = 16384 (end 26443776)

    hipMemsetAsync(he0, 0, 1048576, stream);
    hipMemsetAsync(hd0, 0, 524288, stream);
    hipMemsetAsync(encfl, 0, 409600, stream);  // encfl+decfl+decpr contiguous

    pack_enc_kernel<<<dim3(3, 2048), 256, 0, stream>>>(eWx, eWh, eb, Wencp, bencp);
    pack_dec_kernel<<<dim3(1, 1152), 256, 0, stream>>>(dWh, ow, db, Wdecp, bdecp);
    pack_xb_kernel<<<32768, 256, 0, stream>>>(X, W, A, Xb);

    enc_persist<<<dim3(32, 16), 256, 0, stream>>>(
        Xb, he0, he1, cenc, Wencp, bencp, epi, epf, epo, encfl);

    mid_kernel<<<1024, 256, 0, stream>>>(cenc, noise, zdec, o_z, o_mut, o_lst);
    mix_kernel<<<8, 256, 0, stream>>>(muc, s2c, phic, o_muc, o_s2c, o_phic);

    dec_persist<<<dim3(32, 9), 256, 0, stream>>>(
        hd0, hd1, zdec, Wdecp, bdecp, dpi, dpf, dpo, ob, o_x, o_xraw, decfl, decpr);
}